// Round 4
// baseline (260.493 us; speedup 1.0000x reference)
//
#include <hip/hip_runtime.h>
#include <math.h>

#define N_ANCHOR   900
#define NUM_CAMS   6
#define CDIM       256
#define NUM_LEVELS 4
#define NUM_FIXED  7
#define NUM_LEARN  6
#define NUM_PTS    13
#define NUM_GROUPS 8
#define NW         2496   // NUM_CAMS*NUM_LEVELS*NUM_PTS*NUM_GROUPS
#define NI         312    // NUM_CAMS*NUM_LEVELS*NUM_PTS (softmax axis)
#define SUM_HW     14960

// ---------------------------------------------------------------------------
// Kernel 1: fused q-embed + keypoints + camera projection. grid=900, block=256
// ---------------------------------------------------------------------------
__global__ __launch_bounds__(256) void k_prep(
    const float* __restrict__ inst, const float* __restrict__ anchor,
    const float* __restrict__ l2i, const float* __restrict__ image_wh,
    const float* __restrict__ kp_fixed, const float* __restrict__ kp_w,
    const float* __restrict__ kp_b,
    const float* __restrict__ enc_w, const float* __restrict__ enc_b,
    float* __restrict__ q, float* __restrict__ pts_out,
    float* __restrict__ valid_out) {
  const int n = blockIdx.x;
  const int t = threadIdx.x;
  __shared__ float anc[11];
  __shared__ float learn[NUM_LEARN * 3];
  __shared__ float kps[NUM_PTS][3];
  __shared__ float ins[CDIM];

  const float iv = inst[n * CDIM + t];
  ins[t] = iv;
  if (t < 11) anc[t] = anchor[n * 11 + t];
  __syncthreads();

  // q = inst + anchor @ enc_w + enc_b
  {
    float s = enc_b[t] + iv;
    #pragma unroll
    for (int k = 0; k < 11; ++k) s += anc[k] * enc_w[k * CDIM + t];
    q[n * CDIM + t] = s;
  }

  if (t < NUM_LEARN * 3) {
    float s = kp_b[t];
    for (int k = 0; k < CDIM; ++k) s += ins[k] * kp_w[k * (NUM_LEARN * 3) + t];
    learn[t] = s;
  }
  __syncthreads();

  if (t < NUM_PTS) {
    const float sx = expf(anc[3]), sy = expf(anc[4]), sz = expf(anc[5]);
    float ox, oy, oz;
    if (t < NUM_FIXED) {
      ox = kp_fixed[t * 3 + 0]; oy = kp_fixed[t * 3 + 1]; oz = kp_fixed[t * 3 + 2];
    } else {
      const int j = (t - NUM_FIXED) * 3;
      ox = learn[j + 0]; oy = learn[j + 1]; oz = learn[j + 2];
    }
    ox *= sx; oy *= sy; oz *= sz;
    const float sn = anc[6], cs = anc[7];
    kps[t][0] = cs * ox - sn * oy + anc[0];
    kps[t][1] = sn * ox + cs * oy + anc[1];
    kps[t][2] = oz + anc[2];
  }
  __syncthreads();

  if (t < NUM_CAMS * NUM_PTS) {
    const int cam = t / NUM_PTS, p = t % NUM_PTS;
    const float* M = l2i + cam * 16;
    const float kx = kps[p][0], ky = kps[p][1], kz = kps[p][2];
    const float px = M[0] * kx + M[1] * ky + M[2]  * kz + M[3];
    const float py = M[4] * kx + M[5] * ky + M[6]  * kz + M[7];
    const float pz = M[8] * kx + M[9] * ky + M[10] * kz + M[11];
    const float d = fmaxf(pz, 1e-5f);
    const float u = (px / d) / image_wh[cam * 2 + 0];
    const float v = (py / d) / image_wh[cam * 2 + 1];
    const int o = n * NUM_CAMS * NUM_PTS + t;
    pts_out[o * 2 + 0] = u;
    pts_out[o * 2 + 1] = v;
    valid_out[o] = (pz > 1e-5f) ? 1.0f : 0.0f;
  }
}

// ---------------------------------------------------------------------------
// Kernel 2: tiled GEMM  raw[900][2496] = q[900][256] @ wfc_w[256][2496] + b
// 128x64 tile, 8x4 per thread, K-tile 16. grid = (39, 8), block = 256.
// ---------------------------------------------------------------------------
__global__ __launch_bounds__(256) void k_wgemm(
    const float* __restrict__ q, const float* __restrict__ wfc_w,
    const float* __restrict__ wfc_b, float* __restrict__ raw) {
  const int tid = threadIdx.x;
  const int n0 = blockIdx.x * 64;
  const int m0 = blockIdx.y * 128;
  const int tx = tid & 15, ty = tid >> 4;     // ty: 0..15 -> 8 rows each
  const int br = tid >> 4, bc4 = (tid & 15) * 4;
  __shared__ float AsT[16][132];   // [k][row], pad to 132
  __shared__ float Bs[16][64];
  float acc[8][4] = {{0.f}};

  for (int k0 = 0; k0 < CDIM; k0 += 16) {
    #pragma unroll
    for (int i = 0; i < 2; ++i) {
      const int idx = tid + i * 256;
      const int r = idx >> 2, kg = idx & 3;   // 128 rows x 4 k-groups
      const int row = m0 + r;
      float4 a4 = make_float4(0.f, 0.f, 0.f, 0.f);
      if (row < N_ANCHOR) a4 = *(const float4*)&q[row * CDIM + k0 + kg * 4];
      AsT[kg * 4 + 0][r] = a4.x;
      AsT[kg * 4 + 1][r] = a4.y;
      AsT[kg * 4 + 2][r] = a4.z;
      AsT[kg * 4 + 3][r] = a4.w;
    }
    *(float4*)&Bs[br][bc4] =
        *(const float4*)&wfc_w[(size_t)(k0 + br) * NW + n0 + bc4];
    __syncthreads();
    #pragma unroll
    for (int kk = 0; kk < 16; ++kk) {
      const float4 a0 = *(const float4*)&AsT[kk][ty * 8];
      const float4 a1 = *(const float4*)&AsT[kk][ty * 8 + 4];
      const float4 bv = *(const float4*)&Bs[kk][tx * 4];
      #pragma unroll
      for (int i = 0; i < 4; ++i) {
        const float a = (&a0.x)[i];
        acc[i][0] += a * bv.x; acc[i][1] += a * bv.y;
        acc[i][2] += a * bv.z; acc[i][3] += a * bv.w;
      }
      #pragma unroll
      for (int i = 0; i < 4; ++i) {
        const float a = (&a1.x)[i];
        acc[4 + i][0] += a * bv.x; acc[4 + i][1] += a * bv.y;
        acc[4 + i][2] += a * bv.z; acc[4 + i][3] += a * bv.w;
      }
    }
    __syncthreads();
  }

  const int col = n0 + tx * 4;
  const float4 bias = *(const float4*)&wfc_b[col];
  #pragma unroll
  for (int i = 0; i < 8; ++i) {
    const int row = m0 + ty * 8 + i;
    if (row < N_ANCHOR) {
      float4 o;
      o.x = acc[i][0] + bias.x; o.y = acc[i][1] + bias.y;
      o.z = acc[i][2] + bias.z; o.w = acc[i][3] + bias.w;
      *(float4*)&raw[(size_t)row * NW + col] = o;
    }
  }
}

// ---------------------------------------------------------------------------
// Kernel 3: softmax stats per (anchor, group): max and 1/sum over 312.
// grid = 900, block = 256. stats[n][0..7]=max, [8..15]=1/sum
// ---------------------------------------------------------------------------
__global__ __launch_bounds__(256) void k_smstats(
    const float* __restrict__ raw, float* __restrict__ stats) {
  const int n = blockIdx.x, t = threadIdx.x;
  const int g = t >> 5, lane = t & 31;
  const float* r = raw + (size_t)n * NW;
  float m = -1e30f;
  for (int i = lane; i < NI; i += 32) m = fmaxf(m, r[i * NUM_GROUPS + g]);
  #pragma unroll
  for (int o = 16; o > 0; o >>= 1) m = fmaxf(m, __shfl_down(m, o, 32));
  m = __shfl(m, 0, 32);
  float s = 0.0f;
  for (int i = lane; i < NI; i += 32) s += expf(r[i * NUM_GROUPS + g] - m);
  #pragma unroll
  for (int o = 16; o > 0; o >>= 1) s += __shfl_down(s, o, 32);
  if (lane == 0) {
    stats[n * 16 + g] = m;
    stats[n * 16 + 8 + g] = 1.0f / s;
  }
}

// ---------------------------------------------------------------------------
// Kernel 4: corner-parallel bilinear sampling + weighted aggregation.
// grid = (900, 6), block = 256. wave q = corner, lane ci = 4-channel chunk.
// 2-point unroll over a compacted valid-point list for MLP.
// ---------------------------------------------------------------------------
__global__ __launch_bounds__(256) void k_sample(
    const float* __restrict__ feature,
    const int* __restrict__ spatial_shapes, const int* __restrict__ level_start,
    const float* __restrict__ pts, const float* __restrict__ valid,
    const float* __restrict__ raw, const float* __restrict__ stats,
    float* __restrict__ agg) {
  const int n = blockIdx.x;
  const int cam = blockIdx.y;
  const int t = threadIdx.x;
  const int q = t >> 6;          // corner
  const int ci = t & 63;         // channel chunk (4 channels)
  const int g = ci >> 3;         // group
  __shared__ float w_s[NUM_LEVELS * NUM_PTS * NUM_GROUPS];  // 416
  __shared__ float uv_s[NUM_PTS][2];
  __shared__ float val_s[NUM_PTS];
  __shared__ float mx_s[NUM_GROUPS], inv_s[NUM_GROUPS];
  __shared__ int shp[NUM_LEVELS][2];
  __shared__ int lst[NUM_LEVELS];
  __shared__ int plist[NUM_PTS];
  __shared__ int pcnt;
  __shared__ float4 red[256];

  if (t < NUM_PTS) {
    const int o = (n * NUM_CAMS + cam) * NUM_PTS + t;
    uv_s[t][0] = pts[o * 2 + 0];
    uv_s[t][1] = pts[o * 2 + 1];
    val_s[t] = valid[o];
  }
  if (t < NUM_GROUPS) {
    mx_s[t]  = stats[n * 16 + t];
    inv_s[t] = stats[n * 16 + 8 + t];
  }
  if (t < NUM_LEVELS) {
    shp[t][0] = spatial_shapes[t * 2 + 0];
    shp[t][1] = spatial_shapes[t * 2 + 1];
    lst[t] = level_start[t];
  }
  __syncthreads();
  if (t == 0) {
    int c = 0;
    #pragma unroll
    for (int p = 0; p < NUM_PTS; ++p)
      if (val_s[p] != 0.0f) plist[c++] = p;
    pcnt = c;
  }
  __syncthreads();
  const int cnt = pcnt;

  float* aout = agg + ((size_t)n * NUM_CAMS + cam) * CDIM;
  if (cnt == 0) {
    if (t < 64) *(float4*)&aout[t * 4] = make_float4(0.f, 0.f, 0.f, 0.f);
    return;
  }

  for (int j = t; j < 416; j += 256)
    w_s[j] = expf(raw[(size_t)n * NW + cam * 416 + j] - mx_s[j & 7]) * inv_s[j & 7];
  __syncthreads();

  const int dx = q & 1, dy = q >> 1;
  float4 acc = make_float4(0.f, 0.f, 0.f, 0.f);
  const float* fcam = feature + (size_t)cam * SUM_HW * CDIM;

  for (int j = 0; j < cnt; j += 2) {
    const int p0 = plist[j];
    const int p1 = plist[(j + 1 < cnt) ? (j + 1) : j];
    const bool has1 = (j + 1 < cnt);
    const float u0 = uv_s[p0][0], v0 = uv_s[p0][1];
    const float u1 = uv_s[p1][0], v1 = uv_s[p1][1];
    #pragma unroll
    for (int l = 0; l < NUM_LEVELS; ++l) {
      const int H = shp[l][0], W = shp[l][1], st = lst[l];
      // point 0
      {
        const float x = u0 * (float)W - 0.5f;
        const float y = v0 * (float)H - 0.5f;
        const float x0f = floorf(x), y0f = floorf(y);
        const float wx = x - x0f, wy = y - y0f;
        const int xx = (int)x0f + dx;
        const int yy = (int)y0f + dy;
        if (xx >= 0 && xx < W && yy >= 0 && yy < H) {
          const float cw = w_s[(l * NUM_PTS + p0) * 8 + g]
                         * (dx ? wx : 1.0f - wx) * (dy ? wy : 1.0f - wy);
          const float4 f = *(const float4*)&fcam[(size_t)(st + yy * W + xx) * CDIM + ci * 4];
          acc.x += cw * f.x; acc.y += cw * f.y;
          acc.z += cw * f.z; acc.w += cw * f.w;
        }
      }
      // point 1
      if (has1) {
        const float x = u1 * (float)W - 0.5f;
        const float y = v1 * (float)H - 0.5f;
        const float x0f = floorf(x), y0f = floorf(y);
        const float wx = x - x0f, wy = y - y0f;
        const int xx = (int)x0f + dx;
        const int yy = (int)y0f + dy;
        if (xx >= 0 && xx < W && yy >= 0 && yy < H) {
          const float cw = w_s[(l * NUM_PTS + p1) * 8 + g]
                         * (dx ? wx : 1.0f - wx) * (dy ? wy : 1.0f - wy);
          const float4 f = *(const float4*)&fcam[(size_t)(st + yy * W + xx) * CDIM + ci * 4];
          acc.x += cw * f.x; acc.y += cw * f.y;
          acc.z += cw * f.z; acc.w += cw * f.w;
        }
      }
    }
  }
  red[t] = acc;
  __syncthreads();
  if (t < 64) {
    float4 s = red[t];
    const float4 b1 = red[t + 64], b2 = red[t + 128], b3 = red[t + 192];
    s.x += b1.x + b2.x + b3.x;
    s.y += b1.y + b2.y + b3.y;
    s.z += b1.z + b2.z + b3.z;
    s.w += b1.w + b2.w + b3.w;
    *(float4*)&aout[t * 4] = s;
  }
}

// ---------------------------------------------------------------------------
// Kernel 5: out = inst + (sum_cam agg) @ out_w + out_b. 4 anchors/block.
// grid = 225, block = 256.
// ---------------------------------------------------------------------------
__global__ __launch_bounds__(256) void k_out(
    const float* __restrict__ inst, const float* __restrict__ agg,
    const float* __restrict__ out_w, const float* __restrict__ out_b,
    float* __restrict__ out) {
  const int n0 = blockIdx.x * 4, t = threadIdx.x;
  __shared__ float a_s[4][CDIM];
  #pragma unroll
  for (int a = 0; a < 4; ++a) {
    float s = 0.0f;
    #pragma unroll
    for (int cam = 0; cam < NUM_CAMS; ++cam)
      s += agg[((size_t)(n0 + a) * NUM_CAMS + cam) * CDIM + t];
    a_s[a][t] = s;
  }
  __syncthreads();
  float acc[4];
  #pragma unroll
  for (int a = 0; a < 4; ++a)
    acc[a] = out_b[t] + inst[(size_t)(n0 + a) * CDIM + t];
  for (int k = 0; k < CDIM; ++k) {
    const float w = out_w[k * CDIM + t];
    #pragma unroll
    for (int a = 0; a < 4; ++a) acc[a] += a_s[a][k] * w;
  }
  #pragma unroll
  for (int a = 0; a < 4; ++a)
    out[(size_t)(n0 + a) * CDIM + t] = acc[a];
}

// ---------------------------------------------------------------------------
extern "C" void kernel_launch(void* const* d_in, const int* in_sizes, int n_in,
                              void* d_out, int out_size, void* d_ws, size_t ws_size,
                              hipStream_t stream) {
  const float* inst           = (const float*)d_in[0];
  const float* anchor         = (const float*)d_in[1];
  const float* feature        = (const float*)d_in[3];
  const int*   spatial_shapes = (const int*)d_in[4];
  const int*   level_start    = (const int*)d_in[5];
  const float* l2i            = (const float*)d_in[6];
  const float* image_wh       = (const float*)d_in[7];
  const float* enc_w          = (const float*)d_in[8];
  const float* enc_b          = (const float*)d_in[9];
  const float* kp_fixed       = (const float*)d_in[10];
  const float* kp_w           = (const float*)d_in[11];
  const float* kp_b           = (const float*)d_in[12];
  const float* wfc_w          = (const float*)d_in[13];
  const float* wfc_b          = (const float*)d_in[14];
  const float* out_w          = (const float*)d_in[15];
  const float* out_b          = (const float*)d_in[16];

  float* ws    = (float*)d_ws;
  float* pts   = ws;                                          // 900*78*2
  float* valid = pts + N_ANCHOR * NUM_CAMS * NUM_PTS * 2;     // 900*78
  float* qbuf  = valid + N_ANCHOR * NUM_CAMS * NUM_PTS;       // 900*256
  float* wbuf  = qbuf + N_ANCHOR * CDIM;                      // 900*2496
  float* stats = wbuf + (size_t)N_ANCHOR * NW;                // 900*16
  float* agg   = stats + N_ANCHOR * 16;                       // 900*6*256

  k_prep<<<N_ANCHOR, 256, 0, stream>>>(inst, anchor, l2i, image_wh,
                                       kp_fixed, kp_w, kp_b, enc_w, enc_b,
                                       qbuf, pts, valid);
  k_wgemm<<<dim3(NW / 64, (N_ANCHOR + 127) / 128), 256, 0, stream>>>(
      qbuf, wfc_w, wfc_b, wbuf);
  k_smstats<<<N_ANCHOR, 256, 0, stream>>>(wbuf, stats);
  k_sample<<<dim3(N_ANCHOR, NUM_CAMS), 256, 0, stream>>>(
      feature, spatial_shapes, level_start, pts, valid, wbuf, stats, agg);
  k_out<<<N_ANCHOR / 4, 256, 0, stream>>>(inst, agg, out_w, out_b, (float*)d_out);
}

// Round 5
// 244.689 us; speedup vs baseline: 1.0646x; 1.0646x over previous
//
#include <hip/hip_runtime.h>
#include <math.h>

#define N_ANCHOR   900
#define NUM_CAMS   6
#define CDIM       256
#define NUM_LEVELS 4
#define NUM_FIXED  7
#define NUM_LEARN  6
#define NUM_PTS    13
#define NUM_GROUPS 8
#define NW         2496   // NUM_CAMS*NUM_LEVELS*NUM_PTS*NUM_GROUPS
#define NI         312    // NUM_CAMS*NUM_LEVELS*NUM_PTS (softmax axis)
#define SUM_HW     14960

// ---------------------------------------------------------------------------
// Kernel 1: fused q-embed + keypoints + camera projection. grid=900, block=256
// ---------------------------------------------------------------------------
__global__ __launch_bounds__(256) void k_prep(
    const float* __restrict__ inst, const float* __restrict__ anchor,
    const float* __restrict__ l2i, const float* __restrict__ image_wh,
    const float* __restrict__ kp_fixed, const float* __restrict__ kp_w,
    const float* __restrict__ kp_b,
    const float* __restrict__ enc_w, const float* __restrict__ enc_b,
    float* __restrict__ q, float* __restrict__ pts_out,
    float* __restrict__ valid_out) {
  const int n = blockIdx.x;
  const int t = threadIdx.x;
  __shared__ float anc[11];
  __shared__ float learn[NUM_LEARN * 3];
  __shared__ float kps[NUM_PTS][3];
  __shared__ float ins[CDIM];

  const float iv = inst[n * CDIM + t];
  ins[t] = iv;
  if (t < 11) anc[t] = anchor[n * 11 + t];
  __syncthreads();

  // q = inst + anchor @ enc_w + enc_b
  {
    float s = enc_b[t] + iv;
    #pragma unroll
    for (int k = 0; k < 11; ++k) s += anc[k] * enc_w[k * CDIM + t];
    q[n * CDIM + t] = s;
  }

  if (t < NUM_LEARN * 3) {
    float s = kp_b[t];
    for (int k = 0; k < CDIM; ++k) s += ins[k] * kp_w[k * (NUM_LEARN * 3) + t];
    learn[t] = s;
  }
  __syncthreads();

  if (t < NUM_PTS) {
    const float sx = expf(anc[3]), sy = expf(anc[4]), sz = expf(anc[5]);
    float ox, oy, oz;
    if (t < NUM_FIXED) {
      ox = kp_fixed[t * 3 + 0]; oy = kp_fixed[t * 3 + 1]; oz = kp_fixed[t * 3 + 2];
    } else {
      const int j = (t - NUM_FIXED) * 3;
      ox = learn[j + 0]; oy = learn[j + 1]; oz = learn[j + 2];
    }
    ox *= sx; oy *= sy; oz *= sz;
    const float sn = anc[6], cs = anc[7];
    kps[t][0] = cs * ox - sn * oy + anc[0];
    kps[t][1] = sn * ox + cs * oy + anc[1];
    kps[t][2] = oz + anc[2];
  }
  __syncthreads();

  if (t < NUM_CAMS * NUM_PTS) {
    const int cam = t / NUM_PTS, p = t % NUM_PTS;
    const float* M = l2i + cam * 16;
    const float kx = kps[p][0], ky = kps[p][1], kz = kps[p][2];
    const float px = M[0] * kx + M[1] * ky + M[2]  * kz + M[3];
    const float py = M[4] * kx + M[5] * ky + M[6]  * kz + M[7];
    const float pz = M[8] * kx + M[9] * ky + M[10] * kz + M[11];
    const float d = fmaxf(pz, 1e-5f);
    const float u = (px / d) / image_wh[cam * 2 + 0];
    const float v = (py / d) / image_wh[cam * 2 + 1];
    const int o = n * NUM_CAMS * NUM_PTS + t;
    pts_out[o * 2 + 0] = u;
    pts_out[o * 2 + 1] = v;
    valid_out[o] = (pz > 1e-5f) ? 1.0f : 0.0f;
  }
}

// ---------------------------------------------------------------------------
// Kernel 2: tiled GEMM  raw[900][2496] = q[900][256] @ wfc_w[256][2496] + b
// 64x64 tile, 4x4 per thread, K-tile 16, float4 staging. grid=(39,15), 256 thr
// ---------------------------------------------------------------------------
__global__ __launch_bounds__(256) void k_wgemm(
    const float* __restrict__ q, const float* __restrict__ wfc_w,
    const float* __restrict__ wfc_b, float* __restrict__ raw) {
  const int tid = threadIdx.x;
  const int n0 = blockIdx.x * 64;
  const int m0 = blockIdx.y * 64;
  const int tx = tid & 15, ty = tid >> 4;
  const int ar = tid >> 2, av4 = tid & 3;       // A staging: row, k-group
  const int br = tid >> 4, bc4 = (tid & 15) * 4;// B staging: k-row, col
  __shared__ float AsT[16][68];
  __shared__ float Bs[16][64];
  float acc[4][4] = {{0.f}};

  const int arow = m0 + ar;
  for (int k0 = 0; k0 < CDIM; k0 += 16) {
    float4 a4 = make_float4(0.f, 0.f, 0.f, 0.f);
    if (arow < N_ANCHOR) a4 = *(const float4*)&q[arow * CDIM + k0 + av4 * 4];
    const float4 b4 = *(const float4*)&wfc_w[(size_t)(k0 + br) * NW + n0 + bc4];
    AsT[av4 * 4 + 0][ar] = a4.x;
    AsT[av4 * 4 + 1][ar] = a4.y;
    AsT[av4 * 4 + 2][ar] = a4.z;
    AsT[av4 * 4 + 3][ar] = a4.w;
    *(float4*)&Bs[br][bc4] = b4;
    __syncthreads();
    #pragma unroll
    for (int kk = 0; kk < 16; ++kk) {
      const float4 av = *(const float4*)&AsT[kk][ty * 4];
      const float4 bv = *(const float4*)&Bs[kk][tx * 4];
      acc[0][0] += av.x * bv.x; acc[0][1] += av.x * bv.y;
      acc[0][2] += av.x * bv.z; acc[0][3] += av.x * bv.w;
      acc[1][0] += av.y * bv.x; acc[1][1] += av.y * bv.y;
      acc[1][2] += av.y * bv.z; acc[1][3] += av.y * bv.w;
      acc[2][0] += av.z * bv.x; acc[2][1] += av.z * bv.y;
      acc[2][2] += av.z * bv.z; acc[2][3] += av.z * bv.w;
      acc[3][0] += av.w * bv.x; acc[3][1] += av.w * bv.y;
      acc[3][2] += av.w * bv.z; acc[3][3] += av.w * bv.w;
    }
    __syncthreads();
  }

  const int col = n0 + tx * 4;
  const float4 bias = *(const float4*)&wfc_b[col];
  #pragma unroll
  for (int i = 0; i < 4; ++i) {
    const int row = m0 + ty * 4 + i;
    if (row < N_ANCHOR) {
      float4 o;
      o.x = acc[i][0] + bias.x; o.y = acc[i][1] + bias.y;
      o.z = acc[i][2] + bias.z; o.w = acc[i][3] + bias.w;
      *(float4*)&raw[(size_t)row * NW + col] = o;
    }
  }
}

// ---------------------------------------------------------------------------
// Kernel 3: softmax stats per (anchor, group), row staged via LDS.
// grid = 900, block = 256. stats[n][0..7]=max, [8..15]=1/sum
// ---------------------------------------------------------------------------
__global__ __launch_bounds__(256) void k_smstats(
    const float* __restrict__ raw, float* __restrict__ stats) {
  const int n = blockIdx.x, t = threadIdx.x;
  __shared__ float row_s[NW];
  const float4* src = (const float4*)(raw + (size_t)n * NW);
  for (int j = t; j < NW / 4; j += 256)
    *(float4*)&row_s[j * 4] = src[j];
  __syncthreads();
  const int g = t >> 5, lane = t & 31;
  float m = -1e30f;
  for (int i = lane; i < NI; i += 32) m = fmaxf(m, row_s[i * NUM_GROUPS + g]);
  #pragma unroll
  for (int o = 16; o > 0; o >>= 1) m = fmaxf(m, __shfl_down(m, o, 32));
  m = __shfl(m, 0, 32);
  float s = 0.0f;
  for (int i = lane; i < NI; i += 32) s += expf(row_s[i * NUM_GROUPS + g] - m);
  #pragma unroll
  for (int o = 16; o > 0; o >>= 1) s += __shfl_down(s, o, 32);
  if (lane == 0) {
    stats[n * 16 + g] = m;
    stats[n * 16 + 8 + g] = 1.0f / s;
  }
}

// ---------------------------------------------------------------------------
// Kernel 4: corner-parallel bilinear sampling + weighted aggregation.
// grid = (900, 6), block = 256. wave q = corner, lane ci = 4-channel chunk.
// Writes per-cam slice agg[n][cam][256] (no atomics).
// ---------------------------------------------------------------------------
__global__ __launch_bounds__(256) void k_sample(
    const float* __restrict__ feature,
    const int* __restrict__ spatial_shapes, const int* __restrict__ level_start,
    const float* __restrict__ pts, const float* __restrict__ valid,
    const float* __restrict__ raw, const float* __restrict__ stats,
    float* __restrict__ agg) {
  const int n = blockIdx.x;
  const int cam = blockIdx.y;
  const int t = threadIdx.x;
  const int q = t >> 6;          // corner (one per wave)
  const int ci = t & 63;         // channel chunk: channels 4*ci .. 4*ci+3
  const int g = ci >> 3;         // group of this chunk
  __shared__ float w_s[NUM_LEVELS * NUM_PTS * NUM_GROUPS];  // 416
  __shared__ float uv_s[NUM_PTS][2];
  __shared__ float val_s[NUM_PTS];
  __shared__ float mx_s[NUM_GROUPS], inv_s[NUM_GROUPS];
  __shared__ int shp[NUM_LEVELS][2];
  __shared__ int lst[NUM_LEVELS];
  __shared__ int any_valid;
  __shared__ float4 red[256];

  if (t < NUM_PTS) {
    const int o = (n * NUM_CAMS + cam) * NUM_PTS + t;
    uv_s[t][0] = pts[o * 2 + 0];
    uv_s[t][1] = pts[o * 2 + 1];
    val_s[t] = valid[o];
  }
  if (t < NUM_GROUPS) {
    mx_s[t]  = stats[n * 16 + t];
    inv_s[t] = stats[n * 16 + 8 + t];
  }
  if (t < NUM_LEVELS) {
    shp[t][0] = spatial_shapes[t * 2 + 0];
    shp[t][1] = spatial_shapes[t * 2 + 1];
    lst[t] = level_start[t];
  }
  if (t == 0) any_valid = 0;
  __syncthreads();
  if (t < NUM_PTS && val_s[t] != 0.0f) any_valid = 1;
  __syncthreads();

  float* aout = agg + ((size_t)n * NUM_CAMS + cam) * CDIM;
  if (!any_valid) {
    if (t < 64) *(float4*)&aout[t * 4] = make_float4(0.f, 0.f, 0.f, 0.f);
    return;
  }

  for (int j = t; j < 416; j += 256)
    w_s[j] = expf(raw[(size_t)n * NW + cam * 416 + j] - mx_s[j & 7]) * inv_s[j & 7];
  __syncthreads();

  const int dx = q & 1, dy = q >> 1;
  float4 acc = make_float4(0.f, 0.f, 0.f, 0.f);
  const float* fcam = feature + (size_t)cam * SUM_HW * CDIM;
  for (int p = 0; p < NUM_PTS; ++p) {
    if (val_s[p] == 0.0f) continue;   // block-uniform
    const float u = uv_s[p][0], v = uv_s[p][1];
    #pragma unroll
    for (int l = 0; l < NUM_LEVELS; ++l) {
      const int H = shp[l][0], W = shp[l][1], st = lst[l];
      const float x = u * (float)W - 0.5f;
      const float y = v * (float)H - 0.5f;
      const float x0f = floorf(x), y0f = floorf(y);
      const float wx = x - x0f, wy = y - y0f;
      const int xx = (int)x0f + dx;
      const int yy = (int)y0f + dy;
      if (xx >= 0 && xx < W && yy >= 0 && yy < H) {   // wave-uniform
        const float cw = w_s[(l * NUM_PTS + p) * 8 + g]
                       * (dx ? wx : 1.0f - wx) * (dy ? wy : 1.0f - wy);
        const float4 f = *(const float4*)&fcam[(size_t)(st + yy * W + xx) * CDIM + ci * 4];
        acc.x += cw * f.x; acc.y += cw * f.y;
        acc.z += cw * f.z; acc.w += cw * f.w;
      }
    }
  }
  red[t] = acc;
  __syncthreads();
  if (t < 64) {
    float4 s = red[t];
    const float4 b1 = red[t + 64], b2 = red[t + 128], b3 = red[t + 192];
    s.x += b1.x + b2.x + b3.x;
    s.y += b1.y + b2.y + b3.y;
    s.z += b1.z + b2.z + b3.z;
    s.w += b1.w + b2.w + b3.w;
    *(float4*)&aout[t * 4] = s;
  }
}

// ---------------------------------------------------------------------------
// Kernel 5: out = inst + (sum_cam agg) @ out_w + out_b.
// grid = 900, block = 1024: col = t&255, k-slice = t>>8 (4 slices of 64).
// ---------------------------------------------------------------------------
__global__ __launch_bounds__(1024) void k_out(
    const float* __restrict__ inst, const float* __restrict__ agg,
    const float* __restrict__ out_w, const float* __restrict__ out_b,
    float* __restrict__ out) {
  const int n = blockIdx.x, t = threadIdx.x;
  const int col = t & 255, ks = t >> 8;
  __shared__ float a_s[CDIM];
  __shared__ float red[4][CDIM];

  if (t < CDIM) {
    float s = 0.0f;
    #pragma unroll
    for (int cam = 0; cam < NUM_CAMS; ++cam)
      s += agg[((size_t)n * NUM_CAMS + cam) * CDIM + t];
    a_s[t] = s;
  }
  __syncthreads();

  float partial = 0.0f;
  const int k0 = ks * 64;
  #pragma unroll
  for (int k = 0; k < 64; ++k)
    partial += a_s[k0 + k] * out_w[(k0 + k) * CDIM + col];
  red[ks][col] = partial;
  __syncthreads();

  if (t < CDIM) {
    const float s = red[0][t] + red[1][t] + red[2][t] + red[3][t];
    out[(size_t)n * CDIM + t] = s + out_b[t] + inst[(size_t)n * CDIM + t];
  }
}

// ---------------------------------------------------------------------------
extern "C" void kernel_launch(void* const* d_in, const int* in_sizes, int n_in,
                              void* d_out, int out_size, void* d_ws, size_t ws_size,
                              hipStream_t stream) {
  const float* inst           = (const float*)d_in[0];
  const float* anchor         = (const float*)d_in[1];
  const float* feature        = (const float*)d_in[3];
  const int*   spatial_shapes = (const int*)d_in[4];
  const int*   level_start    = (const int*)d_in[5];
  const float* l2i            = (const float*)d_in[6];
  const float* image_wh       = (const float*)d_in[7];
  const float* enc_w          = (const float*)d_in[8];
  const float* enc_b          = (const float*)d_in[9];
  const float* kp_fixed       = (const float*)d_in[10];
  const float* kp_w           = (const float*)d_in[11];
  const float* kp_b           = (const float*)d_in[12];
  const float* wfc_w          = (const float*)d_in[13];
  const float* wfc_b          = (const float*)d_in[14];
  const float* out_w          = (const float*)d_in[15];
  const float* out_b          = (const float*)d_in[16];

  float* ws    = (float*)d_ws;
  float* pts   = ws;                                          // 900*78*2
  float* valid = pts + N_ANCHOR * NUM_CAMS * NUM_PTS * 2;     // 900*78
  float* qbuf  = valid + N_ANCHOR * NUM_CAMS * NUM_PTS;       // 900*256
  float* wbuf  = qbuf + N_ANCHOR * CDIM;                      // 900*2496
  float* stats = wbuf + (size_t)N_ANCHOR * NW;                // 900*16
  float* agg   = stats + N_ANCHOR * 16;                       // 900*6*256

  k_prep<<<N_ANCHOR, 256, 0, stream>>>(inst, anchor, l2i, image_wh,
                                       kp_fixed, kp_w, kp_b, enc_w, enc_b,
                                       qbuf, pts, valid);
  k_wgemm<<<dim3(NW / 64, (N_ANCHOR + 63) / 64), 256, 0, stream>>>(
      qbuf, wfc_w, wfc_b, wbuf);
  k_smstats<<<N_ANCHOR, 256, 0, stream>>>(wbuf, stats);
  k_sample<<<dim3(N_ANCHOR, NUM_CAMS), 256, 0, stream>>>(
      feature, spatial_shapes, level_start, pts, valid, wbuf, stats, agg);
  k_out<<<N_ANCHOR, 1024, 0, stream>>>(inst, agg, out_w, out_b, (float*)d_out);
}

// Round 6
// 233.082 us; speedup vs baseline: 1.1176x; 1.0498x over previous
//
#include <hip/hip_runtime.h>
#include <math.h>

#define N_ANCHOR   900
#define NUM_CAMS   6
#define CDIM       256
#define NUM_LEVELS 4
#define NUM_FIXED  7
#define NUM_LEARN  6
#define NUM_PTS    13
#define NUM_GROUPS 8
#define NW         2496   // NUM_CAMS*NUM_LEVELS*NUM_PTS*NUM_GROUPS
#define NI         312    // NUM_CAMS*NUM_LEVELS*NUM_PTS (softmax axis)
#define SUM_HW     14960

typedef short short8 __attribute__((ext_vector_type(8)));
typedef float floatx4 __attribute__((ext_vector_type(4)));

__device__ __forceinline__ unsigned short f2bf(float x) {
  unsigned u = __float_as_uint(x);
  u += 0x7FFFu + ((u >> 16) & 1u);   // round-to-nearest-even
  return (unsigned short)(u >> 16);
}

// ---------------------------------------------------------------------------
// Kernel 1: fused q-embed (bf16 out) + keypoints + projection. grid=900, 256
// ---------------------------------------------------------------------------
__global__ __launch_bounds__(256) void k_prep(
    const float* __restrict__ inst, const float* __restrict__ anchor,
    const float* __restrict__ l2i, const float* __restrict__ image_wh,
    const float* __restrict__ kp_fixed, const float* __restrict__ kp_w,
    const float* __restrict__ kp_b,
    const float* __restrict__ enc_w, const float* __restrict__ enc_b,
    unsigned short* __restrict__ qbf, float* __restrict__ pts_out,
    float* __restrict__ valid_out) {
  const int n = blockIdx.x;
  const int t = threadIdx.x;
  __shared__ float anc[11];
  __shared__ float learn[NUM_LEARN * 3];
  __shared__ float kps[NUM_PTS][3];
  __shared__ float ins[CDIM];

  const float iv = inst[n * CDIM + t];
  ins[t] = iv;
  if (t < 11) anc[t] = anchor[n * 11 + t];
  __syncthreads();

  // q = inst + anchor @ enc_w + enc_b  (stored as bf16 for the MFMA GEMM)
  {
    float s = enc_b[t] + iv;
    #pragma unroll
    for (int k = 0; k < 11; ++k) s += anc[k] * enc_w[k * CDIM + t];
    qbf[n * CDIM + t] = f2bf(s);
  }

  if (t < NUM_LEARN * 3) {
    float s = kp_b[t];
    for (int k = 0; k < CDIM; ++k) s += ins[k] * kp_w[k * (NUM_LEARN * 3) + t];
    learn[t] = s;
  }
  __syncthreads();

  if (t < NUM_PTS) {
    const float sx = expf(anc[3]), sy = expf(anc[4]), sz = expf(anc[5]);
    float ox, oy, oz;
    if (t < NUM_FIXED) {
      ox = kp_fixed[t * 3 + 0]; oy = kp_fixed[t * 3 + 1]; oz = kp_fixed[t * 3 + 2];
    } else {
      const int j = (t - NUM_FIXED) * 3;
      ox = learn[j + 0]; oy = learn[j + 1]; oz = learn[j + 2];
    }
    ox *= sx; oy *= sy; oz *= sz;
    const float sn = anc[6], cs = anc[7];
    kps[t][0] = cs * ox - sn * oy + anc[0];
    kps[t][1] = sn * ox + cs * oy + anc[1];
    kps[t][2] = oz + anc[2];
  }
  __syncthreads();

  if (t < NUM_CAMS * NUM_PTS) {
    const int cam = t / NUM_PTS, p = t % NUM_PTS;
    const float* M = l2i + cam * 16;
    const float kx = kps[p][0], ky = kps[p][1], kz = kps[p][2];
    const float px = M[0] * kx + M[1] * ky + M[2]  * kz + M[3];
    const float py = M[4] * kx + M[5] * ky + M[6]  * kz + M[7];
    const float pz = M[8] * kx + M[9] * ky + M[10] * kz + M[11];
    const float d = fmaxf(pz, 1e-5f);
    const float u = (px / d) / image_wh[cam * 2 + 0];
    const float v = (py / d) / image_wh[cam * 2 + 1];
    const int o = n * NUM_CAMS * NUM_PTS + t;
    pts_out[o * 2 + 0] = u;
    pts_out[o * 2 + 1] = v;
    valid_out[o] = (pz > 1e-5f) ? 1.0f : 0.0f;
  }
}

// ---------------------------------------------------------------------------
// Kernel 1b: transpose + convert wfc_w[256][2496] -> wbf_t[2496][256] bf16.
// grid = (39, 4), block = 256: one 64n x 64k tile per block.
// ---------------------------------------------------------------------------
__global__ __launch_bounds__(256) void k_cvtw(
    const float* __restrict__ wfc_w, unsigned short* __restrict__ wbf_t) {
  const int n0 = blockIdx.x * 64, k0 = blockIdx.y * 64;
  const int t = threadIdx.x;
  __shared__ float tile[64][65];
  #pragma unroll
  for (int i = 0; i < 4; ++i) {
    const int kr = (t >> 4) + i * 16;
    const int nc = (t & 15) * 4;
    const float4 v = *(const float4*)&wfc_w[(size_t)(k0 + kr) * NW + n0 + nc];
    tile[kr][nc + 0] = v.x; tile[kr][nc + 1] = v.y;
    tile[kr][nc + 2] = v.z; tile[kr][nc + 3] = v.w;
  }
  __syncthreads();
  #pragma unroll
  for (int i = 0; i < 4; ++i) {
    const int nr = (t >> 4) + i * 16;
    const int kc = (t & 15) * 4;
    ushort4 o;
    o.x = f2bf(tile[kc + 0][nr]);
    o.y = f2bf(tile[kc + 1][nr]);
    o.z = f2bf(tile[kc + 2][nr]);
    o.w = f2bf(tile[kc + 3][nr]);
    *(ushort4*)&wbf_t[(size_t)(n0 + nr) * CDIM + k0 + kc] = o;
  }
}

// ---------------------------------------------------------------------------
// Kernel 2: MFMA GEMM  raw[900][2496] = q[900][256] @ wfc_w[256][2496] + b
// bf16 16x16x32. Block 256 (4 waves), tile M=64 x N=64. grid = (39, 15).
// B staged in LDS with XOR swizzle; A fragments straight from global (L1/L2).
// ---------------------------------------------------------------------------
__global__ __launch_bounds__(256) void k_wgemm(
    const unsigned short* __restrict__ qbf,
    const unsigned short* __restrict__ wbf_t,
    const float* __restrict__ wfc_b, float* __restrict__ raw) {
  const int tid = threadIdx.x;
  const int w = tid >> 6;
  const int l = tid & 63;
  const int n0 = blockIdx.x * 64;
  const int m0 = blockIdx.y * 64;
  __shared__ unsigned short Bs[64 * 64];   // [n][k], k8 XOR-swizzled

  floatx4 acc[4];
  #pragma unroll
  for (int s = 0; s < 4; ++s) acc[s] = (floatx4){0.f, 0.f, 0.f, 0.f};

  const int arow = m0 + w * 16 + (l & 15);
  const bool arow_ok = arow < N_ANCHOR;
  const unsigned short* aptr = qbf + (size_t)arow * CDIM + (l >> 4) * 8;

  for (int k0 = 0; k0 < CDIM; k0 += 64) {
    #pragma unroll
    for (int i = 0; i < 2; ++i) {
      const int idx = tid + i * 256;
      const int n = idx >> 3, kg = idx & 7;
      const short8 bv =
          *(const short8*)&wbf_t[(size_t)(n0 + n) * CDIM + k0 + kg * 8];
      *(short8*)&Bs[n * 64 + ((kg ^ (n & 7)) * 8)] = bv;
    }
    __syncthreads();
    #pragma unroll
    for (int c = 0; c < 2; ++c) {
      short8 a = (short8){0, 0, 0, 0, 0, 0, 0, 0};
      if (arow_ok) a = *(const short8*)&aptr[k0 + c * 32];
      #pragma unroll
      for (int s = 0; s < 4; ++s) {
        const int nloc = s * 16 + (l & 15);
        const int k8 = c * 4 + (l >> 4);
        const short8 b = *(const short8*)&Bs[nloc * 64 + ((k8 ^ (nloc & 7)) * 8)];
        acc[s] = __builtin_amdgcn_mfma_f32_16x16x32_bf16(a, b, acc[s], 0, 0, 0);
      }
    }
    __syncthreads();
  }

  // C/D layout: col = lane&15, row = (lane>>4)*4 + reg
  const int colb = n0 + (l & 15);
  const int rowb = m0 + w * 16 + (l >> 4) * 4;
  #pragma unroll
  for (int s = 0; s < 4; ++s) {
    const int col = colb + s * 16;
    const float bias = wfc_b[col];
    #pragma unroll
    for (int r = 0; r < 4; ++r) {
      const int row = rowb + r;
      if (row < N_ANCHOR)
        raw[(size_t)row * NW + col] = acc[s][r] + bias;
    }
  }
}

// ---------------------------------------------------------------------------
// Kernel 3: softmax stats per (anchor, group), row staged via LDS.
// grid = 900, block = 256. stats[n][0..7]=max, [8..15]=1/sum
// ---------------------------------------------------------------------------
__global__ __launch_bounds__(256) void k_smstats(
    const float* __restrict__ raw, float* __restrict__ stats) {
  const int n = blockIdx.x, t = threadIdx.x;
  __shared__ float row_s[NW];
  const float4* src = (const float4*)(raw + (size_t)n * NW);
  for (int j = t; j < NW / 4; j += 256)
    *(float4*)&row_s[j * 4] = src[j];
  __syncthreads();
  const int g = t >> 5, lane = t & 31;
  float m = -1e30f;
  for (int i = lane; i < NI; i += 32) m = fmaxf(m, row_s[i * NUM_GROUPS + g]);
  #pragma unroll
  for (int o = 16; o > 0; o >>= 1) m = fmaxf(m, __shfl_down(m, o, 32));
  m = __shfl(m, 0, 32);
  float s = 0.0f;
  for (int i = lane; i < NI; i += 32) s += expf(row_s[i * NUM_GROUPS + g] - m);
  #pragma unroll
  for (int o = 16; o > 0; o >>= 1) s += __shfl_down(s, o, 32);
  if (lane == 0) {
    stats[n * 16 + g] = m;
    stats[n * 16 + 8 + g] = 1.0f / s;
  }
}

// ---------------------------------------------------------------------------
// Kernel 4: corner-parallel bilinear sampling + weighted aggregation.
// grid = (900, 6), block = 256. wave q = corner, lane ci = 4-channel chunk.
// ---------------------------------------------------------------------------
__global__ __launch_bounds__(256) void k_sample(
    const float* __restrict__ feature,
    const int* __restrict__ spatial_shapes, const int* __restrict__ level_start,
    const float* __restrict__ pts, const float* __restrict__ valid,
    const float* __restrict__ raw, const float* __restrict__ stats,
    float* __restrict__ agg) {
  const int n = blockIdx.x;
  const int cam = blockIdx.y;
  const int t = threadIdx.x;
  const int q = t >> 6;
  const int ci = t & 63;
  const int g = ci >> 3;
  __shared__ float w_s[NUM_LEVELS * NUM_PTS * NUM_GROUPS];  // 416
  __shared__ float uv_s[NUM_PTS][2];
  __shared__ float val_s[NUM_PTS];
  __shared__ float mx_s[NUM_GROUPS], inv_s[NUM_GROUPS];
  __shared__ int shp[NUM_LEVELS][2];
  __shared__ int lst[NUM_LEVELS];
  __shared__ int any_valid;
  __shared__ float4 red[256];

  if (t < NUM_PTS) {
    const int o = (n * NUM_CAMS + cam) * NUM_PTS + t;
    uv_s[t][0] = pts[o * 2 + 0];
    uv_s[t][1] = pts[o * 2 + 1];
    val_s[t] = valid[o];
  }
  if (t < NUM_GROUPS) {
    mx_s[t]  = stats[n * 16 + t];
    inv_s[t] = stats[n * 16 + 8 + t];
  }
  if (t < NUM_LEVELS) {
    shp[t][0] = spatial_shapes[t * 2 + 0];
    shp[t][1] = spatial_shapes[t * 2 + 1];
    lst[t] = level_start[t];
  }
  if (t == 0) any_valid = 0;
  __syncthreads();
  if (t < NUM_PTS && val_s[t] != 0.0f) any_valid = 1;
  __syncthreads();

  float* aout = agg + ((size_t)n * NUM_CAMS + cam) * CDIM;
  if (!any_valid) {
    if (t < 64) *(float4*)&aout[t * 4] = make_float4(0.f, 0.f, 0.f, 0.f);
    return;
  }

  for (int j = t; j < 416; j += 256)
    w_s[j] = expf(raw[(size_t)n * NW + cam * 416 + j] - mx_s[j & 7]) * inv_s[j & 7];
  __syncthreads();

  const int dx = q & 1, dy = q >> 1;
  float4 acc = make_float4(0.f, 0.f, 0.f, 0.f);
  const float* fcam = feature + (size_t)cam * SUM_HW * CDIM;
  for (int p = 0; p < NUM_PTS; ++p) {
    if (val_s[p] == 0.0f) continue;   // block-uniform
    const float u = uv_s[p][0], v = uv_s[p][1];
    #pragma unroll
    for (int l = 0; l < NUM_LEVELS; ++l) {
      const int H = shp[l][0], W = shp[l][1], st = lst[l];
      const float x = u * (float)W - 0.5f;
      const float y = v * (float)H - 0.5f;
      const float x0f = floorf(x), y0f = floorf(y);
      const float wx = x - x0f, wy = y - y0f;
      const int xx = (int)x0f + dx;
      const int yy = (int)y0f + dy;
      if (xx >= 0 && xx < W && yy >= 0 && yy < H) {   // wave-uniform
        const float cw = w_s[(l * NUM_PTS + p) * 8 + g]
                       * (dx ? wx : 1.0f - wx) * (dy ? wy : 1.0f - wy);
        const float4 f = *(const float4*)&fcam[(size_t)(st + yy * W + xx) * CDIM + ci * 4];
        acc.x += cw * f.x; acc.y += cw * f.y;
        acc.z += cw * f.z; acc.w += cw * f.w;
      }
    }
  }
  red[t] = acc;
  __syncthreads();
  if (t < 64) {
    float4 s = red[t];
    const float4 b1 = red[t + 64], b2 = red[t + 128], b3 = red[t + 192];
    s.x += b1.x + b2.x + b3.x;
    s.y += b1.y + b2.y + b3.y;
    s.z += b1.z + b2.z + b3.z;
    s.w += b1.w + b2.w + b3.w;
    *(float4*)&aout[t * 4] = s;
  }
}

// ---------------------------------------------------------------------------
// Kernel 5: out = inst + (sum_cam agg) @ out_w + out_b.
// grid = 900, block = 1024: col = t&255, k-slice = t>>8.
// ---------------------------------------------------------------------------
__global__ __launch_bounds__(1024) void k_out(
    const float* __restrict__ inst, const float* __restrict__ agg,
    const float* __restrict__ out_w, const float* __restrict__ out_b,
    float* __restrict__ out) {
  const int n = blockIdx.x, t = threadIdx.x;
  const int col = t & 255, ks = t >> 8;
  __shared__ float a_s[CDIM];
  __shared__ float red[4][CDIM];

  if (t < CDIM) {
    float s = 0.0f;
    #pragma unroll
    for (int cam = 0; cam < NUM_CAMS; ++cam)
      s += agg[((size_t)n * NUM_CAMS + cam) * CDIM + t];
    a_s[t] = s;
  }
  __syncthreads();

  float partial = 0.0f;
  const int k0 = ks * 64;
  #pragma unroll
  for (int k = 0; k < 64; ++k)
    partial += a_s[k0 + k] * out_w[(k0 + k) * CDIM + col];
  red[ks][col] = partial;
  __syncthreads();

  if (t < CDIM) {
    const float s = red[0][t] + red[1][t] + red[2][t] + red[3][t];
    out[(size_t)n * CDIM + t] = s + out_b[t] + inst[(size_t)n * CDIM + t];
  }
}

// ---------------------------------------------------------------------------
extern "C" void kernel_launch(void* const* d_in, const int* in_sizes, int n_in,
                              void* d_out, int out_size, void* d_ws, size_t ws_size,
                              hipStream_t stream) {
  const float* inst           = (const float*)d_in[0];
  const float* anchor         = (const float*)d_in[1];
  const float* feature        = (const float*)d_in[3];
  const int*   spatial_shapes = (const int*)d_in[4];
  const int*   level_start    = (const int*)d_in[5];
  const float* l2i            = (const float*)d_in[6];
  const float* image_wh       = (const float*)d_in[7];
  const float* enc_w          = (const float*)d_in[8];
  const float* enc_b          = (const float*)d_in[9];
  const float* kp_fixed       = (const float*)d_in[10];
  const float* kp_w           = (const float*)d_in[11];
  const float* kp_b           = (const float*)d_in[12];
  const float* wfc_w          = (const float*)d_in[13];
  const float* wfc_b          = (const float*)d_in[14];
  const float* out_w          = (const float*)d_in[15];
  const float* out_b          = (const float*)d_in[16];

  float* ws    = (float*)d_ws;
  float* pts   = ws;                                          // 900*78*2
  float* valid = pts + N_ANCHOR * NUM_CAMS * NUM_PTS * 2;     // 900*78
  float* wbuf  = valid + N_ANCHOR * NUM_CAMS * NUM_PTS;       // 900*2496
  float* stats = wbuf + (size_t)N_ANCHOR * NW;                // 900*16
  float* agg   = stats + N_ANCHOR * 16;                       // 900*6*256
  unsigned short* qbf   = (unsigned short*)(agg + N_ANCHOR * NUM_CAMS * CDIM);
  unsigned short* wbf_t = qbf + N_ANCHOR * CDIM;              // 2496*256 bf16

  k_prep<<<N_ANCHOR, 256, 0, stream>>>(inst, anchor, l2i, image_wh,
                                       kp_fixed, kp_w, kp_b, enc_w, enc_b,
                                       qbf, pts, valid);
  k_cvtw<<<dim3(NW / 64, CDIM / 64), 256, 0, stream>>>(wfc_w, wbf_t);
  k_wgemm<<<dim3(NW / 64, (N_ANCHOR + 63) / 64), 256, 0, stream>>>(
      qbf, wbf_t, wfc_b, wbuf);
  k_smstats<<<N_ANCHOR, 256, 0, stream>>>(wbuf, stats);
  k_sample<<<dim3(N_ANCHOR, NUM_CAMS), 256, 0, stream>>>(
      feature, spatial_shapes, level_start, pts, valid, wbuf, stats, agg);
  k_out<<<N_ANCHOR, 1024, 0, stream>>>(inst, agg, out_w, out_b, (float*)d_out);
}

// Round 7
// 213.878 us; speedup vs baseline: 1.2180x; 1.0898x over previous
//
#include <hip/hip_runtime.h>
#include <math.h>

#define N_ANCHOR   900
#define NUM_CAMS   6
#define CDIM       256
#define NUM_LEVELS 4
#define NUM_FIXED  7
#define NUM_LEARN  6
#define NUM_PTS    13
#define NUM_GROUPS 8
#define NW         2496   // NUM_CAMS*NUM_LEVELS*NUM_PTS*NUM_GROUPS
#define NI         312    // NUM_CAMS*NUM_LEVELS*NUM_PTS (softmax axis)
#define SUM_HW     14960

typedef short short8 __attribute__((ext_vector_type(8)));
typedef float floatx4 __attribute__((ext_vector_type(4)));

__device__ __forceinline__ unsigned short f2bf(float x) {
  unsigned u = __float_as_uint(x);
  u += 0x7FFFu + ((u >> 16) & 1u);   // round-to-nearest-even
  return (unsigned short)(u >> 16);
}

// ---------------------------------------------------------------------------
// Kernel 1: fused q-embed (bf16 out) + keypoints + projection. grid=900, 256
// ---------------------------------------------------------------------------
__global__ __launch_bounds__(256) void k_prep(
    const float* __restrict__ inst, const float* __restrict__ anchor,
    const float* __restrict__ l2i, const float* __restrict__ image_wh,
    const float* __restrict__ kp_fixed, const float* __restrict__ kp_w,
    const float* __restrict__ kp_b,
    const float* __restrict__ enc_w, const float* __restrict__ enc_b,
    unsigned short* __restrict__ qbf, float* __restrict__ pts_out,
    float* __restrict__ valid_out) {
  const int n = blockIdx.x;
  const int t = threadIdx.x;
  __shared__ float anc[11];
  __shared__ float learn[NUM_LEARN * 3];
  __shared__ float kps[NUM_PTS][3];
  __shared__ float ins[CDIM];

  const float iv = inst[n * CDIM + t];
  ins[t] = iv;
  if (t < 11) anc[t] = anchor[n * 11 + t];
  __syncthreads();

  // q = inst + anchor @ enc_w + enc_b  (stored as bf16 for the MFMA GEMM)
  {
    float s = enc_b[t] + iv;
    #pragma unroll
    for (int k = 0; k < 11; ++k) s += anc[k] * enc_w[k * CDIM + t];
    qbf[n * CDIM + t] = f2bf(s);
  }

  if (t < NUM_LEARN * 3) {
    float s = kp_b[t];
    for (int k = 0; k < CDIM; ++k) s += ins[k] * kp_w[k * (NUM_LEARN * 3) + t];
    learn[t] = s;
  }
  __syncthreads();

  if (t < NUM_PTS) {
    const float sx = expf(anc[3]), sy = expf(anc[4]), sz = expf(anc[5]);
    float ox, oy, oz;
    if (t < NUM_FIXED) {
      ox = kp_fixed[t * 3 + 0]; oy = kp_fixed[t * 3 + 1]; oz = kp_fixed[t * 3 + 2];
    } else {
      const int j = (t - NUM_FIXED) * 3;
      ox = learn[j + 0]; oy = learn[j + 1]; oz = learn[j + 2];
    }
    ox *= sx; oy *= sy; oz *= sz;
    const float sn = anc[6], cs = anc[7];
    kps[t][0] = cs * ox - sn * oy + anc[0];
    kps[t][1] = sn * ox + cs * oy + anc[1];
    kps[t][2] = oz + anc[2];
  }
  __syncthreads();

  if (t < NUM_CAMS * NUM_PTS) {
    const int cam = t / NUM_PTS, p = t % NUM_PTS;
    const float* M = l2i + cam * 16;
    const float kx = kps[p][0], ky = kps[p][1], kz = kps[p][2];
    const float px = M[0] * kx + M[1] * ky + M[2]  * kz + M[3];
    const float py = M[4] * kx + M[5] * ky + M[6]  * kz + M[7];
    const float pz = M[8] * kx + M[9] * ky + M[10] * kz + M[11];
    const float d = fmaxf(pz, 1e-5f);
    const float u = (px / d) / image_wh[cam * 2 + 0];
    const float v = (py / d) / image_wh[cam * 2 + 1];
    const int o = n * NUM_CAMS * NUM_PTS + t;
    pts_out[o * 2 + 0] = u;
    pts_out[o * 2 + 1] = v;
    valid_out[o] = (pz > 1e-5f) ? 1.0f : 0.0f;
  }
}

// ---------------------------------------------------------------------------
// Kernel 1b: transpose + convert wfc_w[256][2496] -> wbf_t[2496][256] bf16.
// grid = (39, 4), block = 256: one 64n x 64k tile per block.
// ---------------------------------------------------------------------------
__global__ __launch_bounds__(256) void k_cvtw(
    const float* __restrict__ wfc_w, unsigned short* __restrict__ wbf_t) {
  const int n0 = blockIdx.x * 64, k0 = blockIdx.y * 64;
  const int t = threadIdx.x;
  __shared__ float tile[64][65];
  #pragma unroll
  for (int i = 0; i < 4; ++i) {
    const int kr = (t >> 4) + i * 16;
    const int nc = (t & 15) * 4;
    const float4 v = *(const float4*)&wfc_w[(size_t)(k0 + kr) * NW + n0 + nc];
    tile[kr][nc + 0] = v.x; tile[kr][nc + 1] = v.y;
    tile[kr][nc + 2] = v.z; tile[kr][nc + 3] = v.w;
  }
  __syncthreads();
  #pragma unroll
  for (int i = 0; i < 4; ++i) {
    const int nr = (t >> 4) + i * 16;
    const int kc = (t & 15) * 4;
    ushort4 o;
    o.x = f2bf(tile[kc + 0][nr]);
    o.y = f2bf(tile[kc + 1][nr]);
    o.z = f2bf(tile[kc + 2][nr]);
    o.w = f2bf(tile[kc + 3][nr]);
    *(ushort4*)&wbf_t[(size_t)(n0 + nr) * CDIM + k0 + kc] = o;
  }
}

// ---------------------------------------------------------------------------
// Kernel 2: MFMA GEMM  raw[900][2496] = q[900][256] @ wfc_w[256][2496] + b
// bf16 16x16x32. Block 256 (4 waves), tile M=64 x N=64. grid = (39, 15).
// ---------------------------------------------------------------------------
__global__ __launch_bounds__(256) void k_wgemm(
    const unsigned short* __restrict__ qbf,
    const unsigned short* __restrict__ wbf_t,
    const float* __restrict__ wfc_b, float* __restrict__ raw) {
  const int tid = threadIdx.x;
  const int w = tid >> 6;
  const int l = tid & 63;
  const int n0 = blockIdx.x * 64;
  const int m0 = blockIdx.y * 64;
  __shared__ unsigned short Bs[64 * 64];   // [n][k], k8 XOR-swizzled

  floatx4 acc[4];
  #pragma unroll
  for (int s = 0; s < 4; ++s) acc[s] = (floatx4){0.f, 0.f, 0.f, 0.f};

  const int arow = m0 + w * 16 + (l & 15);
  const bool arow_ok = arow < N_ANCHOR;
  const unsigned short* aptr = qbf + (size_t)arow * CDIM + (l >> 4) * 8;

  for (int k0 = 0; k0 < CDIM; k0 += 64) {
    #pragma unroll
    for (int i = 0; i < 2; ++i) {
      const int idx = tid + i * 256;
      const int n = idx >> 3, kg = idx & 7;
      const short8 bv =
          *(const short8*)&wbf_t[(size_t)(n0 + n) * CDIM + k0 + kg * 8];
      *(short8*)&Bs[n * 64 + ((kg ^ (n & 7)) * 8)] = bv;
    }
    __syncthreads();
    #pragma unroll
    for (int c = 0; c < 2; ++c) {
      short8 a = (short8){0, 0, 0, 0, 0, 0, 0, 0};
      if (arow_ok) a = *(const short8*)&aptr[k0 + c * 32];
      #pragma unroll
      for (int s = 0; s < 4; ++s) {
        const int nloc = s * 16 + (l & 15);
        const int k8 = c * 4 + (l >> 4);
        const short8 b = *(const short8*)&Bs[nloc * 64 + ((k8 ^ (nloc & 7)) * 8)];
        acc[s] = __builtin_amdgcn_mfma_f32_16x16x32_bf16(a, b, acc[s], 0, 0, 0);
      }
    }
    __syncthreads();
  }

  // C/D layout: col = lane&15, row = (lane>>4)*4 + reg
  const int colb = n0 + (l & 15);
  const int rowb = m0 + w * 16 + (l >> 4) * 4;
  #pragma unroll
  for (int s = 0; s < 4; ++s) {
    const int col = colb + s * 16;
    const float bias = wfc_b[col];
    #pragma unroll
    for (int r = 0; r < 4; ++r) {
      const int row = rowb + r;
      if (row < N_ANCHOR)
        raw[(size_t)row * NW + col] = acc[s][r] + bias;
    }
  }
}

// ---------------------------------------------------------------------------
// Kernel 3: softmax stats per (anchor, group), row staged via LDS.
// grid = 900, block = 256. stats[n][0..7]=max, [8..15]=1/sum
// ---------------------------------------------------------------------------
__global__ __launch_bounds__(256) void k_smstats(
    const float* __restrict__ raw, float* __restrict__ stats) {
  const int n = blockIdx.x, t = threadIdx.x;
  __shared__ float row_s[NW];
  const float4* src = (const float4*)(raw + (size_t)n * NW);
  for (int j = t; j < NW / 4; j += 256)
    *(float4*)&row_s[j * 4] = src[j];
  __syncthreads();
  const int g = t >> 5, lane = t & 31;
  float m = -1e30f;
  for (int i = lane; i < NI; i += 32) m = fmaxf(m, row_s[i * NUM_GROUPS + g]);
  #pragma unroll
  for (int o = 16; o > 0; o >>= 1) m = fmaxf(m, __shfl_down(m, o, 32));
  m = __shfl(m, 0, 32);
  float s = 0.0f;
  for (int i = lane; i < NI; i += 32) s += expf(row_s[i * NUM_GROUPS + g] - m);
  #pragma unroll
  for (int o = 16; o > 0; o >>= 1) s += __shfl_down(s, o, 32);
  if (lane == 0) {
    stats[n * 16 + g] = m;
    stats[n * 16 + 8 + g] = 1.0f / s;
  }
}

// ---------------------------------------------------------------------------
// Kernel 4: corner-parallel sampling with per-wave compacted job lists.
// grid = (900, 6), block = 256. wave q = corner, lane = 4-channel chunk.
// Phase 1: lanes 0..51 (= p*4+l) build wave-q's valid-corner job list via
// ballot compaction (no OOB loads survive). Phase 2: branch-free 4-deep
// unrolled gather/FMA loop.
// ---------------------------------------------------------------------------
__global__ __launch_bounds__(256) void k_sample(
    const float* __restrict__ feature,
    const int* __restrict__ spatial_shapes, const int* __restrict__ level_start,
    const float* __restrict__ pts, const float* __restrict__ valid,
    const float* __restrict__ raw, const float* __restrict__ stats,
    float* __restrict__ agg) {
  const int n = blockIdx.x;
  const int cam = blockIdx.y;
  const int t = threadIdx.x;
  const int q = t >> 6;          // corner id (per wave)
  const int lane = t & 63;
  const int g = lane >> 3;       // group of this 4-channel chunk
  __shared__ float w_s[NUM_LEVELS * NUM_PTS * NUM_GROUPS];  // 416
  __shared__ float uv_s[NUM_PTS][2];
  __shared__ float val_s[NUM_PTS];
  __shared__ float mx_s[NUM_GROUPS], inv_s[NUM_GROUPS];
  __shared__ int shp[NUM_LEVELS][2];
  __shared__ int lst[NUM_LEVELS];
  __shared__ int any_valid;
  __shared__ int   joff[4][56];
  __shared__ float jcf[4][56];
  __shared__ int   jw[4][56];
  __shared__ float4 red[256];

  if (t < NUM_PTS) {
    const int o = (n * NUM_CAMS + cam) * NUM_PTS + t;
    uv_s[t][0] = pts[o * 2 + 0];
    uv_s[t][1] = pts[o * 2 + 1];
    val_s[t] = valid[o];
  }
  if (t < NUM_GROUPS) {
    mx_s[t]  = stats[n * 16 + t];
    inv_s[t] = stats[n * 16 + 8 + t];
  }
  if (t < NUM_LEVELS) {
    shp[t][0] = spatial_shapes[t * 2 + 0];
    shp[t][1] = spatial_shapes[t * 2 + 1];
    lst[t] = level_start[t];
  }
  if (t == 0) any_valid = 0;
  __syncthreads();
  if (t < NUM_PTS && val_s[t] != 0.0f) any_valid = 1;
  __syncthreads();

  float* aout = agg + ((size_t)n * NUM_CAMS + cam) * CDIM;
  if (!any_valid) {
    if (t < 64) *(float4*)&aout[t * 4] = make_float4(0.f, 0.f, 0.f, 0.f);
    return;
  }

  // softmax-normalized weights for this cam
  for (int j = t; j < 416; j += 256)
    w_s[j] = expf(raw[(size_t)n * NW + cam * 416 + j] - mx_s[j & 7]) * inv_s[j & 7];

  // ---- phase 1: build job list for corner q ----
  bool ok = false;
  int off = 0, wb = 0;
  float cf = 0.0f;
  if (lane < 52) {
    const int p = lane >> 2, l = lane & 3;
    if (val_s[p] != 0.0f) {
      const int H = shp[l][0], W = shp[l][1], st = lst[l];
      const float x = uv_s[p][0] * (float)W - 0.5f;
      const float y = uv_s[p][1] * (float)H - 0.5f;
      const float x0f = floorf(x), y0f = floorf(y);
      const float wx = x - x0f, wy = y - y0f;
      const int dx = q & 1, dy = q >> 1;
      const int xx = (int)x0f + dx;
      const int yy = (int)y0f + dy;
      if (xx >= 0 && xx < W && yy >= 0 && yy < H) {
        ok = true;
        off = (st + yy * W + xx) * CDIM;
        cf = (dx ? wx : 1.0f - wx) * (dy ? wy : 1.0f - wy);
        wb = (l * NUM_PTS + p) * 8;
      }
    }
  }
  const unsigned long long mask = __ballot(ok);
  const int nj = __popcll(mask);
  if (ok) {
    const int pos = __popcll(mask & ((1ull << lane) - 1ull));
    joff[q][pos] = off;
    jcf[q][pos] = cf;
    jw[q][pos] = wb;
  }
  const int padded = (nj + 3) & ~3;
  if (lane >= nj && lane < padded) {
    joff[q][lane] = 0; jcf[q][lane] = 0.0f; jw[q][lane] = 0;
  }
  __syncthreads();

  // ---- phase 2: branch-free gather/accumulate ----
  float4 acc = make_float4(0.f, 0.f, 0.f, 0.f);
  const float* fcam = feature + (size_t)cam * SUM_HW * CDIM;
  const int cio = lane * 4;
  for (int j = 0; j < padded; j += 4) {
    #pragma unroll
    for (int i = 0; i < 4; ++i) {
      const int o = joff[q][j + i];
      const float wgt = jcf[q][j + i] * w_s[jw[q][j + i] + g];
      const float4 f = *(const float4*)&fcam[o + cio];
      acc.x += wgt * f.x; acc.y += wgt * f.y;
      acc.z += wgt * f.z; acc.w += wgt * f.w;
    }
  }
  red[t] = acc;
  __syncthreads();
  if (t < 64) {
    float4 s = red[t];
    const float4 b1 = red[t + 64], b2 = red[t + 128], b3 = red[t + 192];
    s.x += b1.x + b2.x + b3.x;
    s.y += b1.y + b2.y + b3.y;
    s.z += b1.z + b2.z + b3.z;
    s.w += b1.w + b2.w + b3.w;
    *(float4*)&aout[t * 4] = s;
  }
}

// ---------------------------------------------------------------------------
// Kernel 5: out = inst + (sum_cam agg) @ out_w + out_b.
// 2 anchors/block, K-split. grid = 450, block = 1024 (col=t&255, ks=t>>8).
// ---------------------------------------------------------------------------
__global__ __launch_bounds__(1024) void k_out(
    const float* __restrict__ inst, const float* __restrict__ agg,
    const float* __restrict__ out_w, const float* __restrict__ out_b,
    float* __restrict__ out) {
  const int n0 = blockIdx.x * 2, t = threadIdx.x;
  const int col = t & 255, ks = t >> 8;
  __shared__ float a_s[2][CDIM];
  __shared__ float red[4][2][CDIM];

  if (t < 512) {
    const int a = t >> 8, c = t & 255;
    float s = 0.0f;
    #pragma unroll
    for (int cam = 0; cam < NUM_CAMS; ++cam)
      s += agg[((size_t)(n0 + a) * NUM_CAMS + cam) * CDIM + c];
    a_s[a][c] = s;
  }
  __syncthreads();

  float p0 = 0.0f, p1 = 0.0f;
  const int k0 = ks * 64;
  #pragma unroll
  for (int k = 0; k < 64; ++k) {
    const float w = out_w[(k0 + k) * CDIM + col];
    p0 += a_s[0][k0 + k] * w;
    p1 += a_s[1][k0 + k] * w;
  }
  red[ks][0][col] = p0;
  red[ks][1][col] = p1;
  __syncthreads();

  if (t < 512) {
    const int a = t >> 8, c = t & 255;
    const float s = red[0][a][c] + red[1][a][c] + red[2][a][c] + red[3][a][c];
    out[(size_t)(n0 + a) * CDIM + c] = s + out_b[c] + inst[(size_t)(n0 + a) * CDIM + c];
  }
}

// ---------------------------------------------------------------------------
extern "C" void kernel_launch(void* const* d_in, const int* in_sizes, int n_in,
                              void* d_out, int out_size, void* d_ws, size_t ws_size,
                              hipStream_t stream) {
  const float* inst           = (const float*)d_in[0];
  const float* anchor         = (const float*)d_in[1];
  const float* feature        = (const float*)d_in[3];
  const int*   spatial_shapes = (const int*)d_in[4];
  const int*   level_start    = (const int*)d_in[5];
  const float* l2i            = (const float*)d_in[6];
  const float* image_wh       = (const float*)d_in[7];
  const float* enc_w          = (const float*)d_in[8];
  const float* enc_b          = (const float*)d_in[9];
  const float* kp_fixed       = (const float*)d_in[10];
  const float* kp_w           = (const float*)d_in[11];
  const float* kp_b           = (const float*)d_in[12];
  const float* wfc_w          = (const float*)d_in[13];
  const float* wfc_b          = (const float*)d_in[14];
  const float* out_w          = (const float*)d_in[15];
  const float* out_b          = (const float*)d_in[16];

  float* ws    = (float*)d_ws;
  float* pts   = ws;                                          // 900*78*2
  float* valid = pts + N_ANCHOR * NUM_CAMS * NUM_PTS * 2;     // 900*78
  float* wbuf  = valid + N_ANCHOR * NUM_CAMS * NUM_PTS;       // 900*2496
  float* stats = wbuf + (size_t)N_ANCHOR * NW;                // 900*16
  float* agg   = stats + N_ANCHOR * 16;                       // 900*6*256
  unsigned short* qbf   = (unsigned short*)(agg + N_ANCHOR * NUM_CAMS * CDIM);
  unsigned short* wbf_t = qbf + N_ANCHOR * CDIM;              // 2496*256 bf16

  k_prep<<<N_ANCHOR, 256, 0, stream>>>(inst, anchor, l2i, image_wh,
                                       kp_fixed, kp_w, kp_b, enc_w, enc_b,
                                       qbf, pts, valid);
  k_cvtw<<<dim3(NW / 64, CDIM / 64), 256, 0, stream>>>(wfc_w, wbf_t);
  k_wgemm<<<dim3(NW / 64, (N_ANCHOR + 63) / 64), 256, 0, stream>>>(
      qbf, wbf_t, wfc_b, wbuf);
  k_smstats<<<N_ANCHOR, 256, 0, stream>>>(wbuf, stats);
  k_sample<<<dim3(N_ANCHOR, NUM_CAMS), 256, 0, stream>>>(
      feature, spatial_shapes, level_start, pts, valid, wbuf, stats, agg);
  k_out<<<N_ANCHOR / 2, 1024, 0, stream>>>(inst, agg, out_w, out_b, (float*)d_out);
}

// Round 8
// 209.598 us; speedup vs baseline: 1.2428x; 1.0204x over previous
//
#include <hip/hip_runtime.h>
#include <math.h>

#define N_ANCHOR   900
#define NUM_CAMS   6
#define CDIM       256
#define NUM_LEVELS 4
#define NUM_FIXED  7
#define NUM_LEARN  6
#define NUM_PTS    13
#define NUM_GROUPS 8
#define NW         2496   // NUM_CAMS*NUM_LEVELS*NUM_PTS*NUM_GROUPS
#define NI         312    // NUM_CAMS*NUM_LEVELS*NUM_PTS (softmax axis)
#define SUM_HW     14960
#define MAXJOBS    1248   // 6 cams * 4 corners * 52 (pt,level)

typedef short short8 __attribute__((ext_vector_type(8)));
typedef float floatx4 __attribute__((ext_vector_type(4)));

__device__ __forceinline__ unsigned short f2bf(float x) {
  unsigned u = __float_as_uint(x);
  u += 0x7FFFu + ((u >> 16) & 1u);   // round-to-nearest-even
  return (unsigned short)(u >> 16);
}

// ---------------------------------------------------------------------------
// Kernel 1: fused prep (blocks 0..899) + wfc_w transpose/convert (900..1055).
// block = 256.
// ---------------------------------------------------------------------------
__global__ __launch_bounds__(256) void k_pre(
    const float* __restrict__ inst, const float* __restrict__ anchor,
    const float* __restrict__ l2i, const float* __restrict__ image_wh,
    const float* __restrict__ kp_fixed, const float* __restrict__ kp_w,
    const float* __restrict__ kp_b,
    const float* __restrict__ enc_w, const float* __restrict__ enc_b,
    const float* __restrict__ wfc_w,
    unsigned short* __restrict__ qbf, unsigned short* __restrict__ wbf_t,
    float* __restrict__ pts_out, float* __restrict__ valid_out) {
  const int t = threadIdx.x;

  if (blockIdx.x >= N_ANCHOR) {
    // ---- transpose + bf16 convert wfc_w[256][2496] -> wbf_t[2496][256] ----
    const int bi = blockIdx.x - N_ANCHOR;
    const int n0 = (bi % 39) * 64, k0 = (bi / 39) * 64;
    __shared__ float tile[64][65];
    #pragma unroll
    for (int i = 0; i < 4; ++i) {
      const int kr = (t >> 4) + i * 16;
      const int nc = (t & 15) * 4;
      const float4 v = *(const float4*)&wfc_w[(size_t)(k0 + kr) * NW + n0 + nc];
      tile[kr][nc + 0] = v.x; tile[kr][nc + 1] = v.y;
      tile[kr][nc + 2] = v.z; tile[kr][nc + 3] = v.w;
    }
    __syncthreads();
    #pragma unroll
    for (int i = 0; i < 4; ++i) {
      const int nr = (t >> 4) + i * 16;
      const int kc = (t & 15) * 4;
      ushort4 o;
      o.x = f2bf(tile[kc + 0][nr]);
      o.y = f2bf(tile[kc + 1][nr]);
      o.z = f2bf(tile[kc + 2][nr]);
      o.w = f2bf(tile[kc + 3][nr]);
      *(ushort4*)&wbf_t[(size_t)(n0 + nr) * CDIM + k0 + kc] = o;
    }
    return;
  }

  // ---- per-anchor prep ----
  const int n = blockIdx.x;
  __shared__ float anc[11];
  __shared__ float learn[NUM_LEARN * 3];
  __shared__ float psum[8][NUM_LEARN * 3];
  __shared__ float kps[NUM_PTS][3];
  __shared__ float ins[CDIM];

  const float iv = inst[n * CDIM + t];
  ins[t] = iv;
  if (t < 11) anc[t] = anchor[n * 11 + t];
  __syncthreads();

  // q = inst + anchor @ enc_w + enc_b  (stored as bf16 for the MFMA GEMM)
  {
    float s = enc_b[t] + iv;
    #pragma unroll
    for (int k = 0; k < 11; ++k) s += anc[k] * enc_w[k * CDIM + t];
    qbf[n * CDIM + t] = f2bf(s);
  }

  // learn = inst @ kp_w: threads (c,j) c=t/18 (8 k-chunks of 32), j=t%18
  if (t < 144) {
    const int c = t / 18, j = t % 18;
    float s = 0.0f;
    const int k0 = c * 32;
    #pragma unroll
    for (int k = 0; k < 32; ++k)
      s += ins[k0 + k] * kp_w[(k0 + k) * (NUM_LEARN * 3) + j];
    psum[c][j] = s;
  }
  __syncthreads();
  if (t < NUM_LEARN * 3) {
    float s = kp_b[t];
    #pragma unroll
    for (int c = 0; c < 8; ++c) s += psum[c][t];
    learn[t] = s;
  }
  __syncthreads();

  if (t < NUM_PTS) {
    const float sx = expf(anc[3]), sy = expf(anc[4]), sz = expf(anc[5]);
    float ox, oy, oz;
    if (t < NUM_FIXED) {
      ox = kp_fixed[t * 3 + 0]; oy = kp_fixed[t * 3 + 1]; oz = kp_fixed[t * 3 + 2];
    } else {
      const int j = (t - NUM_FIXED) * 3;
      ox = learn[j + 0]; oy = learn[j + 1]; oz = learn[j + 2];
    }
    ox *= sx; oy *= sy; oz *= sz;
    const float sn = anc[6], cs = anc[7];
    kps[t][0] = cs * ox - sn * oy + anc[0];
    kps[t][1] = sn * ox + cs * oy + anc[1];
    kps[t][2] = oz + anc[2];
  }
  __syncthreads();

  if (t < NUM_CAMS * NUM_PTS) {
    const int cam = t / NUM_PTS, p = t % NUM_PTS;
    const float* M = l2i + cam * 16;
    const float kx = kps[p][0], ky = kps[p][1], kz = kps[p][2];
    const float px = M[0] * kx + M[1] * ky + M[2]  * kz + M[3];
    const float py = M[4] * kx + M[5] * ky + M[6]  * kz + M[7];
    const float pz = M[8] * kx + M[9] * ky + M[10] * kz + M[11];
    const float d = fmaxf(pz, 1e-5f);
    const float u = (px / d) / image_wh[cam * 2 + 0];
    const float v = (py / d) / image_wh[cam * 2 + 1];
    const int o = n * NUM_CAMS * NUM_PTS + t;
    pts_out[o * 2 + 0] = u;
    pts_out[o * 2 + 1] = v;
    valid_out[o] = (pz > 1e-5f) ? 1.0f : 0.0f;
  }
}

// ---------------------------------------------------------------------------
// Kernel 2: MFMA GEMM  raw[900][2496] = q[900][256] @ wfc_w[256][2496] + b
// bf16 16x16x32. Block 256 (4 waves), tile M=64 x N=64. grid = (39, 15).
// ---------------------------------------------------------------------------
__global__ __launch_bounds__(256) void k_wgemm(
    const unsigned short* __restrict__ qbf,
    const unsigned short* __restrict__ wbf_t,
    const float* __restrict__ wfc_b, float* __restrict__ raw) {
  const int tid = threadIdx.x;
  const int w = tid >> 6;
  const int l = tid & 63;
  const int n0 = blockIdx.x * 64;
  const int m0 = blockIdx.y * 64;
  __shared__ unsigned short Bs[64 * 64];   // [n][k], k8 XOR-swizzled

  floatx4 acc[4];
  #pragma unroll
  for (int s = 0; s < 4; ++s) acc[s] = (floatx4){0.f, 0.f, 0.f, 0.f};

  const int arow = m0 + w * 16 + (l & 15);
  const bool arow_ok = arow < N_ANCHOR;
  const unsigned short* aptr = qbf + (size_t)arow * CDIM + (l >> 4) * 8;

  for (int k0 = 0; k0 < CDIM; k0 += 64) {
    #pragma unroll
    for (int i = 0; i < 2; ++i) {
      const int idx = tid + i * 256;
      const int n = idx >> 3, kg = idx & 7;
      const short8 bv =
          *(const short8*)&wbf_t[(size_t)(n0 + n) * CDIM + k0 + kg * 8];
      *(short8*)&Bs[n * 64 + ((kg ^ (n & 7)) * 8)] = bv;
    }
    __syncthreads();
    #pragma unroll
    for (int c = 0; c < 2; ++c) {
      short8 a = (short8){0, 0, 0, 0, 0, 0, 0, 0};
      if (arow_ok) a = *(const short8*)&aptr[k0 + c * 32];
      #pragma unroll
      for (int s = 0; s < 4; ++s) {
        const int nloc = s * 16 + (l & 15);
        const int k8 = c * 4 + (l >> 4);
        const short8 b = *(const short8*)&Bs[nloc * 64 + ((k8 ^ (nloc & 7)) * 8)];
        acc[s] = __builtin_amdgcn_mfma_f32_16x16x32_bf16(a, b, acc[s], 0, 0, 0);
      }
    }
    __syncthreads();
  }

  // C/D layout: col = lane&15, row = (lane>>4)*4 + reg
  const int colb = n0 + (l & 15);
  const int rowb = m0 + w * 16 + (l >> 4) * 4;
  #pragma unroll
  for (int s = 0; s < 4; ++s) {
    const int col = colb + s * 16;
    const float bias = wfc_b[col];
    #pragma unroll
    for (int r = 0; r < 4; ++r) {
      const int row = rowb + r;
      if (row < N_ANCHOR)
        raw[(size_t)row * NW + col] = acc[s][r] + bias;
    }
  }
}

// ---------------------------------------------------------------------------
// Kernel 3 (mega): per anchor: softmax stats + weights, block-wide job list
// over all cams/corners, shared-queue gather, reduce, out-GEMV epilogue.
// grid = 900, block = 1024 (16 waves).
// ---------------------------------------------------------------------------
__global__ __launch_bounds__(1024) void k_mega(
    const float* __restrict__ feature,
    const int* __restrict__ spatial_shapes, const int* __restrict__ level_start,
    const float* __restrict__ pts, const float* __restrict__ valid,
    const float* __restrict__ raw,
    const float* __restrict__ inst,
    const float* __restrict__ out_w, const float* __restrict__ out_b,
    float* __restrict__ out) {
  const int n = blockIdx.x;
  const int t = threadIdx.x;
  const int wv = t >> 6;         // wave 0..15
  const int lane = t & 63;       // channel chunk: channels 4*lane..+3
  const int g = lane >> 3;       // group of this chunk

  __shared__ float w_row[NW];              // logits -> softmax weights
  __shared__ float uv_s[NUM_CAMS * NUM_PTS][2];
  __shared__ float val_s[NUM_CAMS * NUM_PTS];
  __shared__ float mx_s[NUM_GROUPS], inv_s[NUM_GROUPS];
  __shared__ int shp[NUM_LEVELS][2];
  __shared__ int lst[NUM_LEVELS];
  __shared__ int joff[MAXJOBS];
  __shared__ float jcf[MAXJOBS];
  __shared__ int jw_s[MAXJOBS];
  __shared__ int njobs;
  __shared__ float4 red4[16][64];
  __shared__ float a_s[CDIM];
  __shared__ float red2[4][CDIM];

  // ---- stage logit row + point data ----
  {
    const float4* src = (const float4*)(raw + (size_t)n * NW);
    for (int j = t; j < NW / 4; j += 1024) *(float4*)&w_row[j * 4] = src[j];
  }
  if (t < NUM_CAMS * NUM_PTS) {
    const int o = n * NUM_CAMS * NUM_PTS + t;
    uv_s[t][0] = pts[o * 2 + 0];
    uv_s[t][1] = pts[o * 2 + 1];
    val_s[t] = valid[o];
  }
  if (t < NUM_LEVELS) {
    shp[t][0] = spatial_shapes[t * 2 + 0];
    shp[t][1] = spatial_shapes[t * 2 + 1];
    lst[t] = level_start[t];
  }
  if (t == 0) njobs = 0;
  __syncthreads();

  // ---- softmax stats (threads 0..255: 8 groups x 32 lanes) ----
  if (t < 256) {
    const int sg = t >> 5, sl = t & 31;
    float m = -1e30f;
    for (int i = sl; i < NI; i += 32) m = fmaxf(m, w_row[i * NUM_GROUPS + sg]);
    #pragma unroll
    for (int o = 16; o > 0; o >>= 1) m = fmaxf(m, __shfl_down(m, o, 32));
    m = __shfl(m, 0, 32);
    float s = 0.0f;
    for (int i = sl; i < NI; i += 32) s += expf(w_row[i * NUM_GROUPS + sg] - m);
    #pragma unroll
    for (int o = 16; o > 0; o >>= 1) s += __shfl_down(s, o, 32);
    if (sl == 0) { mx_s[sg] = m; inv_s[sg] = 1.0f / s; }
  }

  // ---- build job list (all threads; order irrelevant) ----
  for (int jt = t; jt < MAXJOBS; jt += 1024) {
    const int cam = jt / 208;
    const int r = jt % 208;
    const int q = r / 52;
    const int pl = r % 52;
    const int p = pl >> 2, l = pl & 3;
    if (val_s[cam * NUM_PTS + p] != 0.0f) {
      const int H = shp[l][0], W = shp[l][1], st = lst[l];
      const float x = uv_s[cam * NUM_PTS + p][0] * (float)W - 0.5f;
      const float y = uv_s[cam * NUM_PTS + p][1] * (float)H - 0.5f;
      const float x0f = floorf(x), y0f = floorf(y);
      const float wx = x - x0f, wy = y - y0f;
      const int dx = q & 1, dy = q >> 1;
      const int xx = (int)x0f + dx;
      const int yy = (int)y0f + dy;
      if (xx >= 0 && xx < W && yy >= 0 && yy < H) {
        const int pos = atomicAdd(&njobs, 1);
        joff[pos] = (cam * SUM_HW + st + yy * W + xx) * CDIM;
        jcf[pos] = (dx ? wx : 1.0f - wx) * (dy ? wy : 1.0f - wy);
        jw_s[pos] = (cam * 52 + l * NUM_PTS + p) * 8;
      }
    }
  }
  __syncthreads();

  const int nj = njobs;
  const int padded = (nj + 31) & ~31;
  for (int j = nj + t; j < padded; j += 1024) {
    joff[j] = 0; jcf[j] = 0.0f; jw_s[j] = 0;
  }
  // logits -> softmax weights (in place)
  for (int j = t; j < NW; j += 1024)
    w_row[j] = expf(w_row[j] - mx_s[j & 7]) * inv_s[j & 7];
  __syncthreads();

  // ---- shared-queue gather: wave wv handles jobs wv, wv+16, ... ----
  float4 acc = make_float4(0.f, 0.f, 0.f, 0.f);
  const int cio = lane * 4;
  for (int j = wv; j < padded; j += 32) {
    const int o0 = joff[j];
    const float wg0 = jcf[j] * w_row[jw_s[j] + g];
    const float4 f0 = *(const float4*)&feature[o0 + cio];
    const int j1 = j + 16;
    const int o1 = joff[j1];
    const float wg1 = jcf[j1] * w_row[jw_s[j1] + g];
    const float4 f1 = *(const float4*)&feature[o1 + cio];
    acc.x += wg0 * f0.x + wg1 * f1.x;
    acc.y += wg0 * f0.y + wg1 * f1.y;
    acc.z += wg0 * f0.z + wg1 * f1.z;
    acc.w += wg0 * f0.w + wg1 * f1.w;
  }
  red4[wv][lane] = acc;
  __syncthreads();

  // ---- reduce 16 wave-partials -> a_s[256] ----
  if (t < 64) {
    float4 s = red4[0][t];
    #pragma unroll
    for (int w = 1; w < 16; ++w) {
      const float4 b = red4[w][t];
      s.x += b.x; s.y += b.y; s.z += b.z; s.w += b.w;
    }
    *(float4*)&a_s[t * 4] = s;
  }
  __syncthreads();

  // ---- out GEMV: out = inst + a_s @ out_w + out_b (K-split x4) ----
  {
    const int col = t & 255, ks = t >> 8;
    float p = 0.0f;
    const int k0 = ks * 64;
    #pragma unroll
    for (int k = 0; k < 64; ++k)
      p += a_s[k0 + k] * out_w[(k0 + k) * CDIM + col];
    red2[ks][col] = p;
  }
  __syncthreads();
  if (t < CDIM) {
    const float s = red2[0][t] + red2[1][t] + red2[2][t] + red2[3][t];
    out[(size_t)n * CDIM + t] = s + out_b[t] + inst[(size_t)n * CDIM + t];
  }
}

// ---------------------------------------------------------------------------
extern "C" void kernel_launch(void* const* d_in, const int* in_sizes, int n_in,
                              void* d_out, int out_size, void* d_ws, size_t ws_size,
                              hipStream_t stream) {
  const float* inst           = (const float*)d_in[0];
  const float* anchor         = (const float*)d_in[1];
  const float* feature        = (const float*)d_in[3];
  const int*   spatial_shapes = (const int*)d_in[4];
  const int*   level_start    = (const int*)d_in[5];
  const float* l2i            = (const float*)d_in[6];
  const float* image_wh       = (const float*)d_in[7];
  const float* enc_w          = (const float*)d_in[8];
  const float* enc_b          = (const float*)d_in[9];
  const float* kp_fixed       = (const float*)d_in[10];
  const float* kp_w           = (const float*)d_in[11];
  const float* kp_b           = (const float*)d_in[12];
  const float* wfc_w          = (const float*)d_in[13];
  const float* wfc_b          = (const float*)d_in[14];
  const float* out_w          = (const float*)d_in[15];
  const float* out_b          = (const float*)d_in[16];

  float* ws    = (float*)d_ws;
  float* pts   = ws;                                          // 900*78*2
  float* valid = pts + N_ANCHOR * NUM_CAMS * NUM_PTS * 2;     // 900*78
  float* wbuf  = valid + N_ANCHOR * NUM_CAMS * NUM_PTS;       // 900*2496
  unsigned short* qbf   = (unsigned short*)(wbuf + (size_t)N_ANCHOR * NW);
  unsigned short* wbf_t = qbf + N_ANCHOR * CDIM;              // 2496*256 bf16

  k_pre<<<N_ANCHOR + 156, 256, 0, stream>>>(
      inst, anchor, l2i, image_wh, kp_fixed, kp_w, kp_b, enc_w, enc_b,
      wfc_w, qbf, wbf_t, pts, valid);
  k_wgemm<<<dim3(NW / 64, (N_ANCHOR + 63) / 64), 256, 0, stream>>>(
      qbf, wbf_t, wfc_b, wbuf);
  k_mega<<<N_ANCHOR, 1024, 0, stream>>>(
      feature, spatial_shapes, level_start, pts, valid, wbuf,
      inst, out_w, out_b, (float*)d_out);
}

// Round 9
// 198.081 us; speedup vs baseline: 1.3151x; 1.0581x over previous
//
#include <hip/hip_runtime.h>
#include <math.h>

#define N_ANCHOR   900
#define NUM_CAMS   6
#define CDIM       256
#define NUM_LEVELS 4
#define NUM_FIXED  7
#define NUM_LEARN  6
#define NUM_PTS    13
#define NUM_GROUPS 8
#define NW         2496   // NUM_CAMS*NUM_LEVELS*NUM_PTS*NUM_GROUPS
#define NI         312    // NUM_CAMS*NUM_LEVELS*NUM_PTS (softmax axis)
#define SUM_HW     14960
#define MAXJOBS    1248   // 6 cams * 4 corners * 52 (pt,level); divisible by 32
#define WSTRIDE    328    // w_rowT row stride: banks (i + 8g) % 32 -> conflict-free

typedef short short8 __attribute__((ext_vector_type(8)));
typedef float floatx4 __attribute__((ext_vector_type(4)));

__device__ __forceinline__ unsigned short f2bf(float x) {
  unsigned u = __float_as_uint(x);
  u += 0x7FFFu + ((u >> 16) & 1u);   // round-to-nearest-even
  return (unsigned short)(u >> 16);
}

// ---------------------------------------------------------------------------
// Kernel 1: per-anchor prep (blocks 0..899) + wfc_w transpose/cvt (900..1055)
// + out_w transpose/cvt (1056..1071). block = 256.
// ---------------------------------------------------------------------------
__global__ __launch_bounds__(256) void k_pre(
    const float* __restrict__ inst, const float* __restrict__ anchor,
    const float* __restrict__ l2i, const float* __restrict__ image_wh,
    const float* __restrict__ kp_fixed, const float* __restrict__ kp_w,
    const float* __restrict__ kp_b,
    const float* __restrict__ enc_w, const float* __restrict__ enc_b,
    const float* __restrict__ wfc_w, const float* __restrict__ out_w,
    unsigned short* __restrict__ qbf, unsigned short* __restrict__ wbf_t,
    unsigned short* __restrict__ owt,
    float* __restrict__ pts_out, float* __restrict__ valid_out) {
  const int t = threadIdx.x;

  if (blockIdx.x >= N_ANCHOR) {
    // ---- transpose + bf16 convert: src[k][n] (stride ss) -> dst[n][k] ----
    const int bi = blockIdx.x - N_ANCHOR;
    const float* src; unsigned short* dst; int ss, n0, k0;
    if (bi < 156) { src = wfc_w; dst = wbf_t; ss = NW;   n0 = (bi % 39) * 64; k0 = (bi / 39) * 64; }
    else { const int b2 = bi - 156; src = out_w; dst = owt; ss = CDIM; n0 = (b2 % 4) * 64; k0 = (b2 / 4) * 64; }
    __shared__ float tile[64][65];
    #pragma unroll
    for (int i = 0; i < 4; ++i) {
      const int kr = (t >> 4) + i * 16;
      const int nc = (t & 15) * 4;
      const float4 v = *(const float4*)&src[(size_t)(k0 + kr) * ss + n0 + nc];
      tile[kr][nc + 0] = v.x; tile[kr][nc + 1] = v.y;
      tile[kr][nc + 2] = v.z; tile[kr][nc + 3] = v.w;
    }
    __syncthreads();
    #pragma unroll
    for (int i = 0; i < 4; ++i) {
      const int nr = (t >> 4) + i * 16;
      const int kc = (t & 15) * 4;
      ushort4 o;
      o.x = f2bf(tile[kc + 0][nr]);
      o.y = f2bf(tile[kc + 1][nr]);
      o.z = f2bf(tile[kc + 2][nr]);
      o.w = f2bf(tile[kc + 3][nr]);
      *(ushort4*)&dst[(size_t)(n0 + nr) * CDIM + k0 + kc] = o;
    }
    return;
  }

  // ---- per-anchor prep ----
  const int n = blockIdx.x;
  __shared__ float anc[11];
  __shared__ float learn[NUM_LEARN * 3];
  __shared__ float psum[8][NUM_LEARN * 3];
  __shared__ float kps[NUM_PTS][3];
  __shared__ float ins[CDIM];

  const float iv = inst[n * CDIM + t];
  ins[t] = iv;
  if (t < 11) anc[t] = anchor[n * 11 + t];
  __syncthreads();

  {
    float s = enc_b[t] + iv;
    #pragma unroll
    for (int k = 0; k < 11; ++k) s += anc[k] * enc_w[k * CDIM + t];
    qbf[n * CDIM + t] = f2bf(s);
  }

  if (t < 144) {
    const int c = t / 18, j = t % 18;
    float s = 0.0f;
    const int k0 = c * 32;
    #pragma unroll
    for (int k = 0; k < 32; ++k)
      s += ins[k0 + k] * kp_w[(k0 + k) * (NUM_LEARN * 3) + j];
    psum[c][j] = s;
  }
  __syncthreads();
  if (t < NUM_LEARN * 3) {
    float s = kp_b[t];
    #pragma unroll
    for (int c = 0; c < 8; ++c) s += psum[c][t];
    learn[t] = s;
  }
  __syncthreads();

  if (t < NUM_PTS) {
    const float sx = expf(anc[3]), sy = expf(anc[4]), sz = expf(anc[5]);
    float ox, oy, oz;
    if (t < NUM_FIXED) {
      ox = kp_fixed[t * 3 + 0]; oy = kp_fixed[t * 3 + 1]; oz = kp_fixed[t * 3 + 2];
    } else {
      const int j = (t - NUM_FIXED) * 3;
      ox = learn[j + 0]; oy = learn[j + 1]; oz = learn[j + 2];
    }
    ox *= sx; oy *= sy; oz *= sz;
    const float sn = anc[6], cs = anc[7];
    kps[t][0] = cs * ox - sn * oy + anc[0];
    kps[t][1] = sn * ox + cs * oy + anc[1];
    kps[t][2] = oz + anc[2];
  }
  __syncthreads();

  if (t < NUM_CAMS * NUM_PTS) {
    const int cam = t / NUM_PTS, p = t % NUM_PTS;
    const float* M = l2i + cam * 16;
    const float kx = kps[p][0], ky = kps[p][1], kz = kps[p][2];
    const float px = M[0] * kx + M[1] * ky + M[2]  * kz + M[3];
    const float py = M[4] * kx + M[5] * ky + M[6]  * kz + M[7];
    const float pz = M[8] * kx + M[9] * ky + M[10] * kz + M[11];
    const float d = fmaxf(pz, 1e-5f);
    const float u = (px / d) / image_wh[cam * 2 + 0];
    const float v = (py / d) / image_wh[cam * 2 + 1];
    const int o = n * NUM_CAMS * NUM_PTS + t;
    pts_out[o * 2 + 0] = u;
    pts_out[o * 2 + 1] = v;
    valid_out[o] = (pz > 1e-5f) ? 1.0f : 0.0f;
  }
}

// ---------------------------------------------------------------------------
// Kernel 2: MFMA GEMM  raw[900][2496] = q[900][256] @ wfc_w[256][2496] + b
// bf16 16x16x32. Block 256 (4 waves), tile M=64 x N=64. grid = (39, 15).
// ---------------------------------------------------------------------------
__global__ __launch_bounds__(256) void k_wgemm(
    const unsigned short* __restrict__ qbf,
    const unsigned short* __restrict__ wbf_t,
    const float* __restrict__ wfc_b, float* __restrict__ raw) {
  const int tid = threadIdx.x;
  const int w = tid >> 6;
  const int l = tid & 63;
  const int n0 = blockIdx.x * 64;
  const int m0 = blockIdx.y * 64;
  __shared__ unsigned short Bs[64 * 64];

  floatx4 acc[4];
  #pragma unroll
  for (int s = 0; s < 4; ++s) acc[s] = (floatx4){0.f, 0.f, 0.f, 0.f};

  const int arow = m0 + w * 16 + (l & 15);
  const bool arow_ok = arow < N_ANCHOR;
  const unsigned short* aptr = qbf + (size_t)arow * CDIM + (l >> 4) * 8;

  for (int k0 = 0; k0 < CDIM; k0 += 64) {
    #pragma unroll
    for (int i = 0; i < 2; ++i) {
      const int idx = tid + i * 256;
      const int n = idx >> 3, kg = idx & 7;
      const short8 bv =
          *(const short8*)&wbf_t[(size_t)(n0 + n) * CDIM + k0 + kg * 8];
      *(short8*)&Bs[n * 64 + ((kg ^ (n & 7)) * 8)] = bv;
    }
    __syncthreads();
    #pragma unroll
    for (int c = 0; c < 2; ++c) {
      short8 a = (short8){0, 0, 0, 0, 0, 0, 0, 0};
      if (arow_ok) a = *(const short8*)&aptr[k0 + c * 32];
      #pragma unroll
      for (int s = 0; s < 4; ++s) {
        const int nloc = s * 16 + (l & 15);
        const int k8 = c * 4 + (l >> 4);
        const short8 b = *(const short8*)&Bs[nloc * 64 + ((k8 ^ (nloc & 7)) * 8)];
        acc[s] = __builtin_amdgcn_mfma_f32_16x16x32_bf16(a, b, acc[s], 0, 0, 0);
      }
    }
    __syncthreads();
  }

  const int colb = n0 + (l & 15);
  const int rowb = m0 + w * 16 + (l >> 4) * 4;
  #pragma unroll
  for (int s = 0; s < 4; ++s) {
    const int col = colb + s * 16;
    const float bias = wfc_b[col];
    #pragma unroll
    for (int r = 0; r < 4; ++r) {
      const int row = rowb + r;
      if (row < N_ANCHOR)
        raw[(size_t)row * NW + col] = acc[s][r] + bias;
    }
  }
}

// ---------------------------------------------------------------------------
// Kernel 3 (mega): softmax + job list + gather + reduce -> abf (bf16).
// grid = 900, block = 512 (8 waves). ~36 KB LDS -> 4 blocks/CU.
// ---------------------------------------------------------------------------
__global__ __launch_bounds__(512) void k_mega(
    const float* __restrict__ feature,
    const int* __restrict__ spatial_shapes, const int* __restrict__ level_start,
    const float* __restrict__ pts, const float* __restrict__ valid,
    const float* __restrict__ raw,
    unsigned short* __restrict__ abf) {
  const int n = blockIdx.x;
  const int t = threadIdx.x;
  const int wv = t >> 6;         // wave 0..7
  const int lane = t & 63;       // channel chunk: channels 4*lane..+3
  const int g = lane >> 3;       // group of this chunk

  __shared__ float w_rowT[NUM_GROUPS * WSTRIDE];   // [g][i], stride 328
  __shared__ float uv_s[NUM_CAMS * NUM_PTS][2];
  __shared__ float val_s[NUM_CAMS * NUM_PTS];
  __shared__ float mx_s[NUM_GROUPS], inv_s[NUM_GROUPS];
  __shared__ int shp[NUM_LEVELS][2];
  __shared__ int lst[NUM_LEVELS];
  __shared__ int joff[MAXJOBS];
  __shared__ float jcf[MAXJOBS];
  __shared__ short jw_s[MAXJOBS];
  __shared__ int njobs;
  __shared__ float4 red4[8][64];

  // ---- phase 0: stage transposed logits + point data ----
  {
    const float4* src = (const float4*)(raw + (size_t)n * NW);
    for (int j4 = t; j4 < NW / 4; j4 += 512) {
      const float4 v = src[j4];
      const int i = j4 >> 1;           // point-level index
      const int gb = (j4 & 1) * 4;     // group base
      w_rowT[(gb + 0) * WSTRIDE + i] = v.x;
      w_rowT[(gb + 1) * WSTRIDE + i] = v.y;
      w_rowT[(gb + 2) * WSTRIDE + i] = v.z;
      w_rowT[(gb + 3) * WSTRIDE + i] = v.w;
    }
  }
  if (t < NUM_CAMS * NUM_PTS) {
    const int o = n * NUM_CAMS * NUM_PTS + t;
    uv_s[t][0] = pts[o * 2 + 0];
    uv_s[t][1] = pts[o * 2 + 1];
    val_s[t] = valid[o];
  }
  if (t < NUM_LEVELS) {
    shp[t][0] = spatial_shapes[t * 2 + 0];
    shp[t][1] = spatial_shapes[t * 2 + 1];
    lst[t] = level_start[t];
  }
  if (t == 0) njobs = 0;
  __syncthreads();

  // ---- phase 1a: softmax stats (wave wv owns group wv) ----
  {
    const float* wr = &w_rowT[wv * WSTRIDE];
    float m = -1e30f;
    for (int i = lane; i < NI; i += 64) m = fmaxf(m, wr[i]);
    #pragma unroll
    for (int o = 32; o > 0; o >>= 1) m = fmaxf(m, __shfl_down(m, o, 64));
    m = __shfl(m, 0, 64);
    float s = 0.0f;
    for (int i = lane; i < NI; i += 64) s += expf(wr[i] - m);
    #pragma unroll
    for (int o = 32; o > 0; o >>= 1) s += __shfl_down(s, o, 64);
    if (lane == 0) { mx_s[wv] = m; inv_s[wv] = 1.0f / s; }
  }

  // ---- phase 1b: job list via ballot compaction (1 atomic per wave/pass) --
  #pragma unroll
  for (int base = 0; base < MAXJOBS; base += 512) {
    const int jt = base + t;
    bool ok = false;
    int off = 0; short wbi = 0; float cf = 0.0f;
    if (jt < MAXJOBS) {
      const int cam = jt / 208;
      const int r = jt % 208;
      const int q = r / 52;
      const int pl = r % 52;
      const int p = pl >> 2, l = pl & 3;
      if (val_s[cam * NUM_PTS + p] != 0.0f) {
        const int H = shp[l][0], W = shp[l][1], st = lst[l];
        const float x = uv_s[cam * NUM_PTS + p][0] * (float)W - 0.5f;
        const float y = uv_s[cam * NUM_PTS + p][1] * (float)H - 0.5f;
        const float x0f = floorf(x), y0f = floorf(y);
        const float wx = x - x0f, wy = y - y0f;
        const int dx = q & 1, dy = q >> 1;
        const int xx = (int)x0f + dx;
        const int yy = (int)y0f + dy;
        if (xx >= 0 && xx < W && yy >= 0 && yy < H) {
          ok = true;
          off = (cam * SUM_HW + st + yy * W + xx) * CDIM;
          cf = (dx ? wx : 1.0f - wx) * (dy ? wy : 1.0f - wy);
          wbi = (short)(cam * 52 + l * NUM_PTS + p);
        }
      }
    }
    const unsigned long long mask = __ballot(ok);
    const int cnt = __popcll(mask);
    int wbase = 0;
    if (lane == 0 && cnt) wbase = atomicAdd(&njobs, cnt);
    wbase = __shfl(wbase, 0, 64);
    if (ok) {
      const int pos = wbase + __popcll(mask & ((1ull << lane) - 1ull));
      joff[pos] = off; jcf[pos] = cf; jw_s[pos] = wbi;
    }
  }
  __syncthreads();

  // ---- phase 2: pad job list; exp logits in place ----
  const int nj = njobs;
  const int padded = (nj + 31) & ~31;
  for (int j = nj + t; j < padded; j += 512) {
    joff[j] = 0; jcf[j] = 0.0f; jw_s[j] = 0;
  }
  for (int e = t; e < NUM_GROUPS * WSTRIDE; e += 512) {
    const int gg = e / WSTRIDE;
    w_rowT[e] = expf(w_rowT[e] - mx_s[gg]) * inv_s[gg];
  }
  __syncthreads();

  // ---- phase 3: gather, 4 jobs in flight per wave ----
  float4 acc = make_float4(0.f, 0.f, 0.f, 0.f);
  const int cio = lane * 4;
  for (int j = wv; j < padded; j += 32) {
    float4 f[4]; float wg[4];
    #pragma unroll
    for (int i = 0; i < 4; ++i) {
      const int jj = j + i * 8;
      const int o = joff[jj];
      wg[i] = jcf[jj] * w_rowT[g * WSTRIDE + jw_s[jj]];
      f[i] = *(const float4*)&feature[o + cio];
    }
    #pragma unroll
    for (int i = 0; i < 4; ++i) {
      acc.x += wg[i] * f[i].x; acc.y += wg[i] * f[i].y;
      acc.z += wg[i] * f[i].z; acc.w += wg[i] * f[i].w;
    }
  }
  red4[wv][lane] = acc;
  __syncthreads();

  // ---- phase 4: reduce 8 wave-partials -> abf[n][256] (bf16) ----
  if (t < 64) {
    float4 s = red4[0][t];
    #pragma unroll
    for (int w = 1; w < 8; ++w) {
      const float4 b = red4[w][t];
      s.x += b.x; s.y += b.y; s.z += b.z; s.w += b.w;
    }
    ushort4 o;
    o.x = f2bf(s.x); o.y = f2bf(s.y); o.z = f2bf(s.z); o.w = f2bf(s.w);
    *(ushort4*)&abf[(size_t)n * CDIM + t * 4] = o;
  }
}

// ---------------------------------------------------------------------------
// Kernel 4: MFMA GEMM out[900][256] = abf @ owt^T + out_b + inst.
// Same structure as k_wgemm; N=256. grid = (4, 15), block = 256.
// ---------------------------------------------------------------------------
__global__ __launch_bounds__(256) void k_ogemm(
    const unsigned short* __restrict__ abf,
    const unsigned short* __restrict__ owt,
    const float* __restrict__ out_b, const float* __restrict__ inst,
    float* __restrict__ out) {
  const int tid = threadIdx.x;
  const int w = tid >> 6;
  const int l = tid & 63;
  const int n0 = blockIdx.x * 64;
  const int m0 = blockIdx.y * 64;
  __shared__ unsigned short Bs[64 * 64];

  floatx4 acc[4];
  #pragma unroll
  for (int s = 0; s < 4; ++s) acc[s] = (floatx4){0.f, 0.f, 0.f, 0.f};

  const int arow = m0 + w * 16 + (l & 15);
  const bool arow_ok = arow < N_ANCHOR;
  const unsigned short* aptr = abf + (size_t)arow * CDIM + (l >> 4) * 8;

  for (int k0 = 0; k0 < CDIM; k0 += 64) {
    #pragma unroll
    for (int i = 0; i < 2; ++i) {
      const int idx = tid + i * 256;
      const int n = idx >> 3, kg = idx & 7;
      const short8 bv =
          *(const short8*)&owt[(size_t)(n0 + n) * CDIM + k0 + kg * 8];
      *(short8*)&Bs[n * 64 + ((kg ^ (n & 7)) * 8)] = bv;
    }
    __syncthreads();
    #pragma unroll
    for (int c = 0; c < 2; ++c) {
      short8 a = (short8){0, 0, 0, 0, 0, 0, 0, 0};
      if (arow_ok) a = *(const short8*)&aptr[k0 + c * 32];
      #pragma unroll
      for (int s = 0; s < 4; ++s) {
        const int nloc = s * 16 + (l & 15);
        const int k8 = c * 4 + (l >> 4);
        const short8 b = *(const short8*)&Bs[nloc * 64 + ((k8 ^ (nloc & 7)) * 8)];
        acc[s] = __builtin_amdgcn_mfma_f32_16x16x32_bf16(a, b, acc[s], 0, 0, 0);
      }
    }
    __syncthreads();
  }

  const int colb = n0 + (l & 15);
  const int rowb = m0 + w * 16 + (l >> 4) * 4;
  #pragma unroll
  for (int s = 0; s < 4; ++s) {
    const int col = colb + s * 16;
    const float bias = out_b[col];
    #pragma unroll
    for (int r = 0; r < 4; ++r) {
      const int row = rowb + r;
      if (row < N_ANCHOR)
        out[(size_t)row * CDIM + col] =
            acc[s][r] + bias + inst[(size_t)row * CDIM + col];
    }
  }
}

// ---------------------------------------------------------------------------
extern "C" void kernel_launch(void* const* d_in, const int* in_sizes, int n_in,
                              void* d_out, int out_size, void* d_ws, size_t ws_size,
                              hipStream_t stream) {
  const float* inst           = (const float*)d_in[0];
  const float* anchor         = (const float*)d_in[1];
  const float* feature        = (const float*)d_in[3];
  const int*   spatial_shapes = (const int*)d_in[4];
  const int*   level_start    = (const int*)d_in[5];
  const float* l2i            = (const float*)d_in[6];
  const float* image_wh       = (const float*)d_in[7];
  const float* enc_w          = (const float*)d_in[8];
  const float* enc_b          = (const float*)d_in[9];
  const float* kp_fixed       = (const float*)d_in[10];
  const float* kp_w           = (const float*)d_in[11];
  const float* kp_b           = (const float*)d_in[12];
  const float* wfc_w          = (const float*)d_in[13];
  const float* wfc_b          = (const float*)d_in[14];
  const float* out_w          = (const float*)d_in[15];
  const float* out_b          = (const float*)d_in[16];

  float* ws    = (float*)d_ws;
  float* pts   = ws;                                          // 900*78*2
  float* valid = pts + N_ANCHOR * NUM_CAMS * NUM_PTS * 2;     // 900*78
  float* wbuf  = valid + N_ANCHOR * NUM_CAMS * NUM_PTS;       // 900*2496
  unsigned short* qbf   = (unsigned short*)(wbuf + (size_t)N_ANCHOR * NW);
  unsigned short* wbf_t = qbf + N_ANCHOR * CDIM;              // 2496*256
  unsigned short* owt   = wbf_t + (size_t)NW * CDIM;          // 256*256
  unsigned short* abf   = owt + CDIM * CDIM;                  // 900*256

  k_pre<<<N_ANCHOR + 156 + 16, 256, 0, stream>>>(
      inst, anchor, l2i, image_wh, kp_fixed, kp_w, kp_b, enc_w, enc_b,
      wfc_w, out_w, qbf, wbf_t, owt, pts, valid);
  k_wgemm<<<dim3(NW / 64, (N_ANCHOR + 63) / 64), 256, 0, stream>>>(
      qbf, wbf_t, wfc_b, wbuf);
  k_mega<<<N_ANCHOR, 512, 0, stream>>>(
      feature, spatial_shapes, level_start, pts, valid, wbuf, abf);
  k_ogemm<<<dim3(CDIM / 64, (N_ANCHOR + 63) / 64), 256, 0, stream>>>(
      abf, owt, out_b, inst, (float*)d_out);
}